// Round 24
// baseline (440.858 us; speedup 1.0000x reference)
//
#include <hip/hip_runtime.h>
#include <math.h>

#define NB   8
#define NC   192
#define NPIX 3136
#define NPAD 3200
#define NMT  98
#define GRID_LL (NB*NMT)   // 784
#define NIT  25
#define NSP  8
#define GRID_KNN (NB*NIT*NSP)   // 1600
#define GRID_MSG (NB*196)  // 1568
#define FINF 3.4e38f

typedef _Float16 f16x8 __attribute__((ext_vector_type(8)));
typedef float   f32x16 __attribute__((ext_vector_type(16)));

__device__ __forceinline__ float gelu_f(float x){
    float u = 0.7978845608028654f * (x + 0.044715f * x * x * x);
    return 0.5f * x * (1.0f + tanhf(u));
}
__device__ __forceinline__ unsigned short h2u(_Float16 v){
    union { _Float16 f; unsigned short u; } c; c.f = v; return c.u;
}
__device__ __forceinline__ unsigned pack_hi(float a, float b){
    return (unsigned)h2u((_Float16)a) | ((unsigned)h2u((_Float16)b) << 16);
}

// ---------------- min-lex top9 ----------------
#define LESS9(da,ia,db,ib) ((da) < (db) || ((da) == (db) && (ia) < (ib)))
#define CSW9(a,ia,b,ib) { bool sw_ = LESS9(b,ib,a,ia); float tf_=(a); int ti_=(ia); \
    (a) = sw_? (b) : (a); (ia) = sw_? (ib) : (ia); (b) = sw_? tf_ : (b); (ib) = sw_? ti_ : (ib); }

struct Top9 {
    float d0,d1,d2,d3,d4,d5,d6,d7,d8;
    int   j0,j1,j2,j3,j4,j5,j6,j7,j8;
    __device__ __forceinline__ void init(){
        d0=d1=d2=d3=d4=d5=d6=d7=d8=FINF;
        j0=j1=j2=j3=j4=j5=j6=j7=j8=0x7FFFFFFF;
    }
    __device__ __forceinline__ void insert(float nd, int ni){
        if (!LESS9(nd, ni, d8, j8)) return;
        d8 = nd; j8 = ni;
        CSW9(d7,j7,d8,j8); CSW9(d6,j6,d7,j7); CSW9(d5,j5,d6,j6); CSW9(d4,j4,d5,j5);
        CSW9(d3,j3,d4,j4); CSW9(d2,j2,d3,j3); CSW9(d1,j1,d2,j2); CSW9(d0,j0,d1,j1);
    }
};

// ---------------- u32-key top12 (knn screen) ----------------
__device__ __forceinline__ unsigned f2mono(float e){
    unsigned u = __float_as_uint(e);
    return u ^ ((unsigned)((int)u >> 31) | 0x80000000u);
}
__device__ __forceinline__ float unmono(unsigned m){
    return __uint_as_float(m ^ ((unsigned)(((int)~m) >> 31) | 0x80000000u));
}

#define CSK(a,b) { unsigned h_ = (a) > (b) ? (a) : (b); unsigned l_ = (a) > (b) ? (b) : (a); (a) = h_; (b) = l_; }
#define INSKEY(x_) if ((x_) > t_k11){ t_k11 = (x_); \
    CSK(t_k10,t_k11) CSK(t_k9,t_k10) CSK(t_k8,t_k9) CSK(t_k7,t_k8) \
    CSK(t_k6,t_k7) CSK(t_k5,t_k6) CSK(t_k4,t_k5) CSK(t_k3,t_k4) \
    CSK(t_k2,t_k3) CSK(t_k1,t_k2) CSK(t_k0,t_k1) }

#define KQ(A,Q) { \
    unsigned q0_ = (f2mono(A[4*(Q)+0]) & 0xFFFFF000u) | (unsigned)(jinvb_ - 8*(Q)    ); \
    unsigned q1_ = (f2mono(A[4*(Q)+1]) & 0xFFFFF000u) | (unsigned)(jinvb_ - 8*(Q) - 1); \
    unsigned q2_ = (f2mono(A[4*(Q)+2]) & 0xFFFFF000u) | (unsigned)(jinvb_ - 8*(Q) - 2); \
    unsigned q3_ = (f2mono(A[4*(Q)+3]) & 0xFFFFF000u) | (unsigned)(jinvb_ - 8*(Q) - 3); \
    unsigned qa_ = q0_ > q1_ ? q0_ : q1_; \
    unsigned qb_ = q2_ > q3_ ? q2_ : q3_; \
    unsigned qm_ = qa_ > qb_ ? qa_ : qb_; \
    if (qm_ > t_k11){ INSKEY(q0_) INSKEY(q1_) INSKEY(q2_) INSKEY(q3_) } }

#define AMAX16(A) fmaxf(fmaxf(fmaxf(fmaxf(A[0],A[1]),fmaxf(A[2],A[3])),fmaxf(fmaxf(A[4],A[5]),fmaxf(A[6],A[7]))), \
                        fmaxf(fmaxf(fmaxf(A[8],A[9]),fmaxf(A[10],A[11])),fmaxf(fmaxf(A[12],A[13]),fmaxf(A[14],A[15]))))

#define INSACCK(A,JS) { float am_ = AMAX16(A); \
    if (am_ >= thrf){ int jinvb_ = 4095 - (jg + (JS)*32 + 4*h); \
        KQ(A,0) KQ(A,1) KQ(A,2) KQ(A,3) } }

#define MF(ACC,AO,BO) ACC = __builtin_amdgcn_mfma_f32_32x32x16_f16(AO,BO,ACC,0,0,0);
#define ZERO16 {0,0,0,0,0,0,0,0,0,0,0,0,0,0,0,0}

// ---------------------------------------------------------------------------
// wt: W1,W2 fp32 -> transposed [K][192] fp32 (for FMA ll2). 32x32 LDS tiles.
// ---------------------------------------------------------------------------
__global__ __launch_bounds__(256) void wt_kernel(
    const float* __restrict__ W1, const float* __restrict__ W2,
    float* __restrict__ W1T, float* __restrict__ W2T)
{
    __shared__ float tile[32*33];
    int t = blockIdx.x;
    const float* src; float* dst;
    if (t < 36){ src = W1; dst = W1T; } else { src = W2; dst = W2T; t -= 36; }
    int tr = t / 6, tc = t - tr*6;
    int tid = threadIdx.x;
    {
        int i = tid >> 3, j4 = (tid & 7)*4;
        float4 v = *(const float4*)&src[(size_t)(tr*32 + i)*192 + tc*32 + j4];
        tile[i*33 + j4+0] = v.x; tile[i*33 + j4+1] = v.y;
        tile[i*33 + j4+2] = v.z; tile[i*33 + j4+3] = v.w;
    }
    __syncthreads();
    {
        int j = tid >> 3, i4 = (tid & 7)*4;
        float4 o = make_float4(tile[(i4+0)*33 + j], tile[(i4+1)*33 + j],
                               tile[(i4+2)*33 + j], tile[(i4+3)*33 + j]);
        *(float4*)&dst[(size_t)(tc*32 + j)*192 + tr*32 + i4] = o;
    }
}

// ---------------------------------------------------------------------------
// wt16: Wg,W3,W4 fp32 -> fp16 hi/lo concat [Wg|W3|W4], row-major [n][K].
// ---------------------------------------------------------------------------
__global__ __launch_bounds__(256) void wt16_kernel(
    const float* __restrict__ Wg, const float* __restrict__ W3,
    const float* __restrict__ W4,
    unsigned short* __restrict__ Wh, unsigned short* __restrict__ Wl)
{
    int i = blockIdx.x*256 + threadIdx.x;
    if (i >= 147456) return;
    const float* src; int off;
    if (i < 73728)       { src = Wg; off = i; }
    else if (i < 110592) { src = W3; off = i - 73728; }
    else                 { src = W4; off = i - 110592; }
    float w = src[off];
    _Float16 hi = (_Float16)w;
    Wh[i] = h2u(hi);
    Wl[i] = h2u((_Float16)(w - (float)hi));
}

// ---------------------------------------------------------------------------
// pad: Xh pad rows = 0, S2h pad = fp16(-30000).
// ---------------------------------------------------------------------------
__global__ __launch_bounds__(256) void pad_kernel(
    unsigned short* __restrict__ Xh, unsigned short* __restrict__ S2h)
{
    const int b = blockIdx.x;
    const int tid = threadIdx.x;
    uint4 z = make_uint4(0,0,0,0);
    for (int e = tid; e < 1536; e += 256){
        int r = e / 24, c8 = (e % 24) * 8;
        *(uint4*)&Xh[((size_t)b*NPAD + NPIX + r)*192 + c8] = z;
    }
    if (tid < 64){
        union { _Float16 f; unsigned short u; } p;
        p.f = (_Float16)(-30000.0f);
        S2h[(size_t)b*NPAD + NPIX + tid] = p.u;
    }
}

// ---------------------------------------------------------------------------
// FMA lorentz_linear (R17-proven), col-major activations.
// ---------------------------------------------------------------------------
template<int K, bool WCM, bool DUAL, bool AX, bool CONVF>
__global__ __launch_bounds__(256, 4) void ll2_kernel(
    const float* __restrict__ A0, const float* __restrict__ A1,
    const float* __restrict__ WT, const float* __restrict__ bias,
    const float* __restrict__ sptr, const float* __restrict__ Xres,
    float* __restrict__ OutCM, float* __restrict__ Hrm,
    unsigned short* __restrict__ Xh, unsigned short* __restrict__ S2h,
    float* __restrict__ SQf)
{
    __shared__ float lA[32*36];
    __shared__ float lW[32*196];

    const int tid = threadIdx.x;
    const int tx = tid & 15, ty = tid >> 4;
    const int bid = blockIdx.x;
    const int b  = bid / NMT;
    const int n0 = (bid % NMT) * 32;

    float acc[2][12];
    #pragma unroll
    for (int mi = 0; mi < 2; ++mi)
        #pragma unroll
        for (int j = 0; j < 12; ++j) acc[mi][j] = 0.f;

    for (int kt = 0; kt < K/32; ++kt){
        {
            int kk = tid >> 3;
            int m4 = (tid & 7) * 4;
            int c  = kt*32 + kk;
            const float* pl;
            if (K > 192 && c >= 192) pl = A1 + ((size_t)b*192 + (c - 192))*NPIX;
            else                     pl = A0 + ((size_t)b*192 + c)*NPIX;
            float4 v = *(const float4*)&pl[n0 + m4];
            v.x = gelu_f(v.x); v.y = gelu_f(v.y); v.z = gelu_f(v.z); v.w = gelu_f(v.w);
            *(float4*)&lA[kk*36 + m4] = v;
        }
        #pragma unroll
        for (int r = 0; r < 6; ++r){
            int e  = tid + r*256;
            int kk = e / 48;
            int c4 = (e - kk*48) * 4;
            float4 v = *(const float4*)&WT[(size_t)(kt*32 + kk)*192 + c4];
            *(float4*)&lW[kk*196 + c4] = v;
        }
        __syncthreads();
        #pragma unroll
        for (int kk = 0; kk < 32; ++kk){
            float2 a2 = *(const float2*)&lA[kk*36 + ty*2];
            float4 w0 = *(const float4*)&lW[kk*196 + tx*12];
            float4 w1 = *(const float4*)&lW[kk*196 + tx*12 + 4];
            float4 w2 = *(const float4*)&lW[kk*196 + tx*12 + 8];
            float aw[2]  = {a2.x, a2.y};
            float wv[12] = {w0.x,w0.y,w0.z,w0.w, w1.x,w1.y,w1.z,w1.w, w2.x,w2.y,w2.z,w2.w};
            #pragma unroll
            for (int mi = 0; mi < 2; ++mi)
                #pragma unroll
                for (int j = 0; j < 12; ++j)
                    acc[mi][j] = fmaf(aw[mi], wv[j], acc[mi][j]);
        }
        __syncthreads();
    }

    const int lane = tid & 63;
    float es = expf(sptr[0]);
    float bv[12];
    #pragma unroll
    for (int q = 0; q < 3; ++q){
        float4 t4 = *(const float4*)&bias[tx*12 + q*4];
        bv[q*4+0] = t4.x; bv[q*4+1] = t4.y; bv[q*4+2] = t4.z; bv[q*4+3] = t4.w;
    }
    #pragma unroll
    for (int mi = 0; mi < 2; ++mi){
        float part = 0.f;
        #pragma unroll
        for (int j = 0; j < 12; ++j){
            float y = acc[mi][j] + bv[j];
            acc[mi][j] = y;
            if (!(tx == 0 && j == 0)) part += y * y;
        }
        #pragma unroll
        for (int m = 1; m < 16; m <<= 1) part += __shfl_xor(part, m, 64);
        float y0   = __shfl(acc[mi][0], lane & 48, 64);
        float tval = es / (1.f + expf(-y0)) + 1.1f;
        float denom = fmaxf(part, 1e-8f);
        float sca  = (tval*tval - 1.f) / denom;
        float sqs  = sqrtf(sca);
        #pragma unroll
        for (int j = 0; j < 12; ++j){
            float o = acc[mi][j] * sqs;
            if (tx == 0 && j == 0) o = tval;
            acc[mi][j] = o;
        }
    }
    if (AX){
        #pragma unroll
        for (int j = 0; j < 12; ++j){
            int c = tx*12 + j;
            float2 xv = *(const float2*)&Xres[((size_t)b*192 + c)*NPIX + n0 + ty*2];
            acc[0][j] += xv.x; acc[1][j] += xv.y;
        }
    }
    if (WCM){
        #pragma unroll
        for (int j = 0; j < 12; ++j){
            int c = tx*12 + j;
            *(float2*)&OutCM[((size_t)b*192 + c)*NPIX + n0 + ty*2] = make_float2(acc[0][j], acc[1][j]);
        }
    }
    if (DUAL){
        #pragma unroll
        for (int mi = 0; mi < 2; ++mi){
            #pragma unroll
            for (int q = 0; q < 3; ++q){
                float4 o = make_float4(acc[mi][q*4+0], acc[mi][q*4+1], acc[mi][q*4+2], acc[mi][q*4+3]);
                *(float4*)&Hrm[((size_t)b*NPIX + n0 + ty*2 + mi)*192 + tx*12 + q*4] = o;
            }
        }
    }
    if (CONVF){
        #pragma unroll
        for (int mi = 0; mi < 2; ++mi){
            int row = n0 + ty*2 + mi;
            float s = 0.f;
            #pragma unroll
            for (int j = 0; j < 12; ++j) s = fmaf(acc[mi][j], acc[mi][j], s);
            #pragma unroll
            for (int m = 1; m < 16; m <<= 1) s += __shfl_xor(s, m, 64);
            #pragma unroll
            for (int q = 0; q < 3; ++q){
                uint2 hv;
                hv.x = pack_hi(acc[mi][q*4+0], acc[mi][q*4+1]);
                hv.y = pack_hi(acc[mi][q*4+2], acc[mi][q*4+3]);
                *(uint2*)&Xh[((size_t)b*NPAD + row)*192 + tx*12 + q*4] = hv;
            }
            if (tx == 0){
                SQf[(size_t)b*NPIX + row] = s;
                S2h[(size_t)b*NPAD + row] = h2u((_Float16)(-0.5f * s));
            }
        }
    }
}

// ---------------------------------------------------------------------------
// Fused MFMA chain: LLg -> LL3 -> LL4 in one kernel; inter-layer 32x192 fp32
// tiles in LDS (stride 198 = conflict-free). LL4 residuals: x (global cm) +
// X2f (= tileA, LDS). Output col-major.
// ---------------------------------------------------------------------------
#define MLL_EPI(O0,O1,ACC0,ACC1,BIAS,SPTR) { \
    const float es_ = expf((SPTR)[0]); \
    const float bv0_ = (BIAS)[c0], bv1_ = (BIAS)[c1]; \
    float p_[16]; \
    _Pragma("unroll") for (int r = 0; r < 16; ++r){ \
        O0[r] = ACC0[r] + bv0_; O1[r] = ACC1[r] + bv1_; \
        p_[r] = O0[r]*O0[r] + O1[r]*O1[r]; } \
    _Pragma("unroll") for (int m_ = 1; m_ < 32; m_ <<= 1){ \
        _Pragma("unroll") for (int r = 0; r < 16; ++r) p_[r] += __shfl_xor(p_[r], m_, 64); } \
    if (l31 == 0){ \
        _Pragma("unroll") for (int r = 0; r < 16; ++r){ \
            int row = (r&3) + 8*(r>>2) + 4*h; \
            float v = p_[r]; \
            if (w == 0){ v -= O0[r]*O0[r]; y0v[row] = O0[r]; } \
            psum[w][row] = v; } } \
    __syncthreads(); \
    _Pragma("unroll") for (int r = 0; r < 16; ++r){ \
        int row = (r&3) + 8*(r>>2) + 4*h; \
        float S_ = psum[0][row] + psum[1][row] + psum[2][row]; \
        float y0_ = y0v[row]; \
        float tv_ = es_ / (1.f + expf(-y0_)) + 1.1f; \
        float dn_ = fmaxf(S_, 1e-8f); \
        float sq_ = sqrtf((tv_*tv_ - 1.f)/dn_); \
        O0[r] *= sq_; O1[r] *= sq_; \
        if (w == 0 && l31 == 0) O0[r] = tv_; } \
    __syncthreads(); }

#define GSPLIT8(SRC,AH,AL) { \
    _Pragma("unroll") for (int e_ = 0; e_ < 8; ++e_){ \
        float gg_ = gelu_f((SRC)[e_]); \
        _Float16 hi_ = (_Float16)gg_; \
        AH[e_] = hi_; AL[e_] = (_Float16)(gg_ - (float)hi_); } }

__global__ __launch_bounds__(192) void mfuse_kernel(
    const float* __restrict__ Hrm, const float* __restrict__ Msg,
    const unsigned short* __restrict__ Wgh, const unsigned short* __restrict__ Wgl,
    const unsigned short* __restrict__ W3h, const unsigned short* __restrict__ W3l,
    const unsigned short* __restrict__ W4h, const unsigned short* __restrict__ W4l,
    const float* __restrict__ bg, const float* __restrict__ sg,
    const float* __restrict__ b3, const float* __restrict__ s3,
    const float* __restrict__ b4, const float* __restrict__ s4,
    const float* __restrict__ x, float* __restrict__ out)
{
    __shared__ float psum[3][32], y0v[32];
    __shared__ float tileA[32*198];
    __shared__ float tileB[32*198];

    const int tid = threadIdx.x;
    const int w = tid >> 6, lane = tid & 63, l31 = lane & 31, h = lane >> 5;
    const int bid = blockIdx.x;
    const int b = bid / NMT, mt = bid % NMT;
    const int row0 = mt*32;
    const int nb = w*64;
    const size_t arow = (size_t)b*NPIX + row0 + l31;
    const int c0 = nb + l31, c1 = nb + 32 + l31;

    float o0[16], o1[16];

    // ---------------- Stage 1: LLg (K=384, A = gelu(Hrm|Msg)) ----------------
    {
        f32x16 acc0 = ZERO16, acc1 = ZERO16;
        #pragma unroll
        for (int ks = 0; ks < 24; ++ks){
            const int kb = ks*16 + h*8;
            const float* src = (ks < 12) ? (Hrm + arow*192 + kb) : (Msg + arow*192 + (kb - 192));
            float g[8];
            *(float4*)&g[0] = *(const float4*)src;
            *(float4*)&g[4] = *(const float4*)(src + 4);
            f16x8 ah, al;
            GSPLIT8(g, ah, al)
            f16x8 wh0 = __builtin_bit_cast(f16x8, *(const uint4*)&Wgh[(size_t)c0*384 + kb]);
            f16x8 wl0 = __builtin_bit_cast(f16x8, *(const uint4*)&Wgl[(size_t)c0*384 + kb]);
            f16x8 wh1 = __builtin_bit_cast(f16x8, *(const uint4*)&Wgh[(size_t)c1*384 + kb]);
            f16x8 wl1 = __builtin_bit_cast(f16x8, *(const uint4*)&Wgl[(size_t)c1*384 + kb]);
            MF(acc0, ah, wh0) MF(acc0, al, wh0) MF(acc0, ah, wl0)
            MF(acc1, ah, wh1) MF(acc1, al, wh1) MF(acc1, ah, wl1)
        }
        MLL_EPI(o0, o1, acc0, acc1, bg, sg)
        #pragma unroll
        for (int r = 0; r < 16; ++r){
            int row = (r&3) + 8*(r>>2) + 4*h;
            tileA[row*198 + c0] = o0[r];
            tileA[row*198 + c1] = o1[r];
        }
        __syncthreads();
    }

    // ---------------- Stage 2: LL3 (K=192, A = gelu(tileA)) ----------------
    {
        f32x16 acc0 = ZERO16, acc1 = ZERO16;
        #pragma unroll
        for (int ks = 0; ks < 12; ++ks){
            const int kb = ks*16 + h*8;
            float g[8];
            #pragma unroll
            for (int e = 0; e < 8; ++e) g[e] = tileA[l31*198 + kb + e];
            f16x8 ah, al;
            GSPLIT8(g, ah, al)
            f16x8 wh0 = __builtin_bit_cast(f16x8, *(const uint4*)&W3h[(size_t)c0*192 + kb]);
            f16x8 wl0 = __builtin_bit_cast(f16x8, *(const uint4*)&W3l[(size_t)c0*192 + kb]);
            f16x8 wh1 = __builtin_bit_cast(f16x8, *(const uint4*)&W3h[(size_t)c1*192 + kb]);
            f16x8 wl1 = __builtin_bit_cast(f16x8, *(const uint4*)&W3l[(size_t)c1*192 + kb]);
            MF(acc0, ah, wh0) MF(acc0, al, wh0) MF(acc0, ah, wl0)
            MF(acc1, ah, wh1) MF(acc1, al, wh1) MF(acc1, ah, wl1)
        }
        MLL_EPI(o0, o1, acc0, acc1, b3, s3)
        #pragma unroll
        for (int r = 0; r < 16; ++r){
            int row = (r&3) + 8*(r>>2) + 4*h;
            tileB[row*198 + c0] = o0[r];
            tileB[row*198 + c1] = o1[r];
        }
        __syncthreads();
    }

    // ---------------- Stage 3: LL4 (K=192, A = gelu(tileB)) ----------------
    {
        f32x16 acc0 = ZERO16, acc1 = ZERO16;
        #pragma unroll
        for (int ks = 0; ks < 12; ++ks){
            const int kb = ks*16 + h*8;
            float g[8];
            #pragma unroll
            for (int e = 0; e < 8; ++e) g[e] = tileB[l31*198 + kb + e];
            f16x8 ah, al;
            GSPLIT8(g, ah, al)
            f16x8 wh0 = __builtin_bit_cast(f16x8, *(const uint4*)&W4h[(size_t)c0*192 + kb]);
            f16x8 wl0 = __builtin_bit_cast(f16x8, *(const uint4*)&W4l[(size_t)c0*192 + kb]);
            f16x8 wh1 = __builtin_bit_cast(f16x8, *(const uint4*)&W4h[(size_t)c1*192 + kb]);
            f16x8 wl1 = __builtin_bit_cast(f16x8, *(const uint4*)&W4l[(size_t)c1*192 + kb]);
            MF(acc0, ah, wh0) MF(acc0, al, wh0) MF(acc0, ah, wl0)
            MF(acc1, ah, wh1) MF(acc1, al, wh1) MF(acc1, ah, wl1)
        }
        MLL_EPI(o0, o1, acc0, acc1, b4, s4)
        // residuals: x (global col-major) + X2f (tileA)
        #pragma unroll
        for (int r = 0; r < 16; ++r){
            int row = (r&3) + 8*(r>>2) + 4*h;
            o0[r] += tileA[row*198 + c0];
            o1[r] += tileA[row*198 + c1];
        }
        #pragma unroll
        for (int p4 = 0; p4 < 4; ++p4){
            float4 xv0 = *(const float4*)&x[((size_t)b*192 + c0)*NPIX + row0 + 8*p4 + 4*h];
            float4 xv1 = *(const float4*)&x[((size_t)b*192 + c1)*NPIX + row0 + 8*p4 + 4*h];
            o0[4*p4+0] += xv0.x; o0[4*p4+1] += xv0.y; o0[4*p4+2] += xv0.z; o0[4*p4+3] += xv0.w;
            o1[4*p4+0] += xv1.x; o1[4*p4+1] += xv1.y; o1[4*p4+2] += xv1.z; o1[4*p4+3] += xv1.w;
        }
        #pragma unroll
        for (int p4 = 0; p4 < 4; ++p4){
            *(float4*)&out[((size_t)b*192 + c0)*NPIX + row0 + 8*p4 + 4*h] =
                make_float4(o0[4*p4+0], o0[4*p4+1], o0[4*p4+2], o0[4*p4+3]);
            *(float4*)&out[((size_t)b*192 + c1)*NPIX + row0 + 8*p4 + 4*h] =
                make_float4(o1[4*p4+0], o1[4*p4+1], o1[4*p4+2], o1[4*p4+3]);
        }
    }
}

// ---------------------------------------------------------------------------
// MFMA kNN screen (R21 double-buffered version).
// ---------------------------------------------------------------------------
__global__ __launch_bounds__(256) __attribute__((amdgpu_waves_per_eu(2))) void knn_kernel(
    const unsigned short* __restrict__ Xh, const unsigned short* __restrict__ S2h,
    unsigned* __restrict__ PK)
{
    __shared__ uint4 lds[2][640];

    const int tid  = threadIdx.x;
    const int lane = tid & 63;
    const int w    = tid >> 6;
    const int l31  = lane & 31;
    const int h    = lane >> 5;
    const int bid  = blockIdx.x;
    const int b    = bid & 7;
    const int t2   = bid >> 3;
    const int itile = t2 >> 3;
    const int sp    = t2 & 7;
    const int i0    = itile * 128;
    const int g0 = (sp*25)/NSP, g1 = ((sp+1)*25)/NSP;
    const size_t rowb = (size_t)b * NPAD;

    const size_t bbase = (rowb + i0 + w*32 + l31)*192;
    f16x8 B[6][2];
    #pragma unroll
    for (int kc = 0; kc < 6; ++kc)
        #pragma unroll
        for (int ks = 0; ks < 2; ++ks)
            B[kc][ks] = __builtin_bit_cast(f16x8, *(const uint4*)&Xh[bbase + kc*32 + (ks*2 + h)*8]);

    unsigned t_k0=0,t_k1=0,t_k2=0,t_k3=0,t_k4=0,t_k5=0,
             t_k6=0,t_k7=0,t_k8=0,t_k9=0,t_k10=0,t_k11=0;
    float thrf = -FINF;

    const int rs0 = tid >> 2, seg0 = tid & 3;
    const int wr0 = rs0*5 + seg0, wr1 = (rs0 + 64)*5 + seg0;

    uint4 pv0 = *(const uint4*)&Xh[(rowb + g0*128 + rs0)*192 + seg0*8];
    uint4 pv1 = *(const uint4*)&Xh[(rowb + g0*128 + rs0 + 64)*192 + seg0*8];

    for (int g = g0; g < g1; ++g){
        const int jg = g*128;
        f32x16 acc0 = ZERO16, acc1 = ZERO16, acc2 = ZERO16, acc3 = ZERO16;

        #pragma unroll
        for (int kc = 0; kc < 6; ++kc){
            const int buf = kc & 1;
            lds[buf][wr0] = pv0;
            lds[buf][wr1] = pv1;
            {
                int nkc = (kc < 5) ? kc + 1 : 0;
                int njg = (kc < 5) ? jg : jg + 128;
                if (kc < 5 || g + 1 < g1){
                    pv0 = *(const uint4*)&Xh[(rowb + njg + rs0)*192 + nkc*32 + seg0*8];
                    pv1 = *(const uint4*)&Xh[(rowb + njg + rs0 + 64)*192 + nkc*32 + seg0*8];
                }
            }
            __syncthreads();
            #pragma unroll
            for (int ks = 0; ks < 2; ++ks){
                int rb = l31*5 + (ks*2 + h);
                f16x8 bh = B[kc][ks];
                f16x8 a0h = __builtin_bit_cast(f16x8, lds[buf][  0 + rb]);
                f16x8 a1h = __builtin_bit_cast(f16x8, lds[buf][160 + rb]);
                f16x8 a2h = __builtin_bit_cast(f16x8, lds[buf][320 + rb]);
                f16x8 a3h = __builtin_bit_cast(f16x8, lds[buf][480 + rb]);
                MF(acc0, a0h, bh)
                MF(acc1, a1h, bh)
                MF(acc2, a2h, bh)
                MF(acc3, a3h, bh)
            }
        }

        {
            unsigned m  = (h == 0) ? 0xFFFFFFFFu : 0u;
            unsigned om = 0x3C00u & m;
            f16x8 one = __builtin_bit_cast(f16x8, make_uint4(om, 0, 0, 0));
            unsigned s0 = (unsigned)S2h[rowb + jg +  0 + l31];
            unsigned s1 = (unsigned)S2h[rowb + jg + 32 + l31];
            unsigned s2 = (unsigned)S2h[rowb + jg + 64 + l31];
            unsigned s3 = (unsigned)S2h[rowb + jg + 96 + l31];
            f16x8 a;
            a = __builtin_bit_cast(f16x8, make_uint4(s0 & m, 0,0,0)); MF(acc0, a, one)
            a = __builtin_bit_cast(f16x8, make_uint4(s1 & m, 0,0,0)); MF(acc1, a, one)
            a = __builtin_bit_cast(f16x8, make_uint4(s2 & m, 0,0,0)); MF(acc2, a, one)
            a = __builtin_bit_cast(f16x8, make_uint4(s3 & m, 0,0,0)); MF(acc3, a, one)
        }

        INSACCK(acc0, 0)
        INSACCK(acc1, 1)
        INSACCK(acc2, 2)
        INSACCK(acc3, 3)
        thrf = (t_k11 != 0u) ? unmono(t_k11 & 0xFFFFF000u) : -FINF;
    }

    #define MRGK(Kk) { unsigned ok_ = __shfl((int)(Kk), lane ^ 32, 64); \
                      if (lane < 32) { INSKEY((unsigned)ok_) } }
    MRGK(t_k0) MRGK(t_k1) MRGK(t_k2) MRGK(t_k3) MRGK(t_k4) MRGK(t_k5)
    MRGK(t_k6) MRGK(t_k7) MRGK(t_k8) MRGK(t_k9) MRGK(t_k10) MRGK(t_k11)

    if (lane < 32){
        size_t po = ((size_t)(t2*8 + b)*128 + (size_t)w*32 + l31)*12;
        PK[po+ 0] = t_k0;  PK[po+ 1] = t_k1;  PK[po+ 2] = t_k2;  PK[po+ 3] = t_k3;
        PK[po+ 4] = t_k4;  PK[po+ 5] = t_k5;  PK[po+ 6] = t_k6;  PK[po+ 7] = t_k7;
        PK[po+ 8] = t_k8;  PK[po+ 9] = t_k9;  PK[po+10] = t_k10; PK[po+11] = t_k11;
    }
}

// ---------------------------------------------------------------------------
// 8-way key merge -> approx top-16 -> exact fp32 rescore -> top-9
// -> max-message, Msg fp32 ROW-MAJOR [m][192].
// ---------------------------------------------------------------------------
__global__ __launch_bounds__(256) void merge_msg_kernel(
    const float* __restrict__ H, const float* __restrict__ SQf,
    const unsigned* __restrict__ PK, float* __restrict__ Msg)
{
    __shared__ float liX[16*196];
    __shared__ unsigned kv[1600];
    __shared__ float cd[256];
    __shared__ int   cidx[256];
    __shared__ int   fidx[144];

    const int tid = threadIdx.x;
    const int bid = blockIdx.x;
    const int b  = bid / 196;
    const int i0 = (bid % 196) * 16;
    const int base = b * NPIX;

    #pragma unroll
    for (int k = 0; k < 3; ++k){
        int f = tid + k*256;
        int r = f / 48, c4 = f % 48;
        *(float4*)&liX[r*196 + c4*4] = *(const float4*)&H[(size_t)(base + i0 + r)*192 + c4*4];
    }
    if (tid < 128){
        int r = tid >> 3, sp = tid & 7;
        int i = i0 + r;
        size_t po = ((size_t)(((i>>7)*NSP + sp)*8 + b)*128 + (i & 127))*12;
        #pragma unroll
        for (int q = 0; q < 3; ++q)
            *(uint4*)&kv[r*100 + sp*12 + q*4] = *(const uint4*)&PK[po + q*4];
    }
    __syncthreads();

    if (tid < 16){
        int r = tid;
        int h0=0,h1=0,h2=0,h3=0,h4=0,h5=0,h6=0,h7=0;
        #pragma unroll
        for (int p = 0; p < 16; ++p){
            unsigned bk = 0; int bs = 0;
#define HEADC(SP,HV) { \
            unsigned k_ = (HV < 12) ? kv[r*100 + SP*12 + HV] : 0u; \
            bool bt_ = k_ > bk; \
            bk = bt_? k_ : bk; bs = bt_? SP : bs; }
            HEADC(0,h0) HEADC(1,h1) HEADC(2,h2) HEADC(3,h3)
            HEADC(4,h4) HEADC(5,h5) HEADC(6,h6) HEADC(7,h7)
#undef HEADC
            cidx[r*16 + p] = 4095 - (int)(bk & 0xFFFu);
            h0 += (bs==0); h1 += (bs==1); h2 += (bs==2); h3 += (bs==3);
            h4 += (bs==4); h5 += (bs==5); h6 += (bs==6); h7 += (bs==7);
        }
    }
    __syncthreads();

    {
        int r = tid >> 4, p = tid & 15;
        int j = cidx[r*16 + p];
        const float* hj = &H[(size_t)(base + j)*192];
        float dot = 0.f;
        #pragma unroll
        for (int q = 0; q < 48; ++q){
            float4 xv = *(const float4*)&liX[r*196 + q*4];
            float4 yv = *(const float4*)&hj[q*4];
            dot = fmaf(xv.x,yv.x, fmaf(xv.y,yv.y, fmaf(xv.z,yv.z, fmaf(xv.w,yv.w, dot))));
        }
        cd[r*16 + p] = SQf[base + j] - 2.f*dot;
    }
    __syncthreads();

    if (tid < 16){
        int r = tid;
        Top9 m; m.init();
        #pragma unroll
        for (int c = 0; c < 16; ++c) m.insert(cd[r*16 + c], cidx[r*16 + c]);
        fidx[r*9+0]=m.j0; fidx[r*9+1]=m.j1; fidx[r*9+2]=m.j2; fidx[r*9+3]=m.j3;
        fidx[r*9+4]=m.j4; fidx[r*9+5]=m.j5; fidx[r*9+6]=m.j6; fidx[r*9+7]=m.j7;
        fidx[r*9+8]=m.j8;
    }
    __syncthreads();

    int rr = tid >> 4, part = tid & 15;
    int ii = i0 + rr;
    int nbr[9];
    #pragma unroll
    for (int e = 0; e < 9; ++e) nbr[e] = fidx[rr*9 + e];
    #pragma unroll
    for (int q = 0; q < 3; ++q){
        float4 mv = make_float4(-FINF, -FINF, -FINF, -FINF);
        #pragma unroll
        for (int e = 0; e < 9; ++e){
            float4 v = *(const float4*)&H[(size_t)(base + nbr[e])*192 + part*12 + q*4];
            mv.x = fmaxf(mv.x, v.x); mv.y = fmaxf(mv.y, v.y);
            mv.z = fmaxf(mv.z, v.z); mv.w = fmaxf(mv.w, v.w);
        }
        float4 xi = *(const float4*)&liX[rr*196 + part*12 + q*4];
        *(float4*)&Msg[(size_t)(base + ii)*192 + part*12 + q*4] =
            make_float4(mv.x - xi.x, mv.y - xi.y, mv.z - xi.z, mv.w - xi.w);
    }
}

extern "C" void kernel_launch(void* const* d_in, const int* in_sizes, int n_in,
                              void* d_out, int out_size, void* d_ws, size_t ws_size,
                              hipStream_t stream)
{
    const float* x  = (const float*)d_in[0];
    const float* W1 = (const float*)d_in[1];
    const float* b1 = (const float*)d_in[2];
    const float* s1 = (const float*)d_in[3];
    const float* W2 = (const float*)d_in[4];
    const float* b2 = (const float*)d_in[5];
    const float* s2 = (const float*)d_in[6];
    const float* Wg = (const float*)d_in[7];
    const float* bg = (const float*)d_in[8];
    const float* sg = (const float*)d_in[9];
    const float* W3 = (const float*)d_in[10];
    const float* b3 = (const float*)d_in[11];
    const float* s3 = (const float*)d_in[12];
    const float* W4 = (const float*)d_in[13];
    const float* b4 = (const float*)d_in[14];
    const float* s4 = (const float*)d_in[15];
    float* ws = (float*)d_ws;
    float* out = (float*)d_out;

    const size_t NE = (size_t)NB*NPIX*192;
    float* T1cm = ws;
    float* Msg  = ws;
    float* Hrm  = ws + NE;
    unsigned short* Xh  = (unsigned short*)(ws + 3*NE);
    unsigned short* S2h = Xh + (size_t)NB*NPAD*192;
    float* SQf = (float*)(S2h + (size_t)NB*NPAD);
    unsigned* PK = (unsigned*)(SQf + (size_t)NB*NPIX);
    float* W1T = (float*)(PK + (size_t)GRID_KNN*128*12);
    float* W2T = W1T + 36864;
    unsigned short* Wh16 = (unsigned short*)(W2T + 36864);
    unsigned short* Wl16 = Wh16 + 147456;
    const unsigned short* Wgh = Wh16,          *Wgl = Wl16;
    const unsigned short* W3h = Wh16 + 73728,  *W3l = Wl16 + 73728;
    const unsigned short* W4h = Wh16 + 110592, *W4l = Wl16 + 110592;

    wt_kernel<<<72, 256, 0, stream>>>(W1, W2, W1T, W2T);
    wt16_kernel<<<576, 256, 0, stream>>>(Wg, W3, W4, Wh16, Wl16);
    pad_kernel<<<NB, 256, 0, stream>>>(Xh, S2h);
    // LL1 (FMA): x -> T1cm
    ll2_kernel<192, true , false, false, false><<<GRID_LL, 256, 0, stream>>>(
        x, x, W1T, b1, s1, nullptr, T1cm, nullptr, nullptr, nullptr, nullptr);
    // LL2 (FMA): T1cm -> Hrm (+x residual) + conv outputs
    ll2_kernel<192, false, true , true , true ><<<GRID_LL, 256, 0, stream>>>(
        T1cm, T1cm, W2T, b2, s2, x, nullptr, Hrm, Xh, S2h, SQf);
    // graph conv
    knn_kernel<<<GRID_KNN, 256, 0, stream>>>(Xh, S2h, PK);
    merge_msg_kernel<<<GRID_MSG, 256, 0, stream>>>(Hrm, SQf, PK, Msg);
    // fused LLg -> LL3 -> LL4 (MFMA), output col-major = (B,C,H,W) native
    mfuse_kernel<<<GRID_LL, 192, 0, stream>>>(
        Hrm, Msg, Wgh, Wgl, W3h, W3l, W4h, W4l,
        bg, sg, b3, s3, b4, s4, x, out);
}

// Round 25
// 440.490 us; speedup vs baseline: 1.0008x; 1.0008x over previous
//
#include <hip/hip_runtime.h>
#include <math.h>

#define NB   8
#define NC   192
#define NPIX 3136
#define NPAD 3200
#define NMT  98
#define GRID_LL (NB*NMT)   // 784
#define NIT  25
#define NSP  8
#define GRID_KNN (NB*NIT*NSP)   // 1600
#define GRID_MSG (NB*196)  // 1568
#define FINF 3.4e38f

typedef _Float16 f16x8 __attribute__((ext_vector_type(8)));
typedef float   f32x16 __attribute__((ext_vector_type(16)));

__device__ __forceinline__ float gelu_f(float x){
    float u = 0.7978845608028654f * (x + 0.044715f * x * x * x);
    return 0.5f * x * (1.0f + tanhf(u));
}
__device__ __forceinline__ unsigned short h2u(_Float16 v){
    union { _Float16 f; unsigned short u; } c; c.f = v; return c.u;
}
__device__ __forceinline__ unsigned pack_hi(float a, float b){
    return (unsigned)h2u((_Float16)a) | ((unsigned)h2u((_Float16)b) << 16);
}

// ---------------- min-lex top9 ----------------
#define LESS9(da,ia,db,ib) ((da) < (db) || ((da) == (db) && (ia) < (ib)))
#define CSW9(a,ia,b,ib) { bool sw_ = LESS9(b,ib,a,ia); float tf_=(a); int ti_=(ia); \
    (a) = sw_? (b) : (a); (ia) = sw_? (ib) : (ia); (b) = sw_? tf_ : (b); (ib) = sw_? ti_ : (ib); }

struct Top9 {
    float d0,d1,d2,d3,d4,d5,d6,d7,d8;
    int   j0,j1,j2,j3,j4,j5,j6,j7,j8;
    __device__ __forceinline__ void init(){
        d0=d1=d2=d3=d4=d5=d6=d7=d8=FINF;
        j0=j1=j2=j3=j4=j5=j6=j7=j8=0x7FFFFFFF;
    }
    __device__ __forceinline__ void insert(float nd, int ni){
        if (!LESS9(nd, ni, d8, j8)) return;
        d8 = nd; j8 = ni;
        CSW9(d7,j7,d8,j8); CSW9(d6,j6,d7,j7); CSW9(d5,j5,d6,j6); CSW9(d4,j4,d5,j5);
        CSW9(d3,j3,d4,j4); CSW9(d2,j2,d3,j3); CSW9(d1,j1,d2,j2); CSW9(d0,j0,d1,j1);
    }
};

// ---------------- u32-key top12 (knn screen) ----------------
__device__ __forceinline__ unsigned f2mono(float e){
    unsigned u = __float_as_uint(e);
    return u ^ ((unsigned)((int)u >> 31) | 0x80000000u);
}
__device__ __forceinline__ float unmono(unsigned m){
    return __uint_as_float(m ^ ((unsigned)(((int)~m) >> 31) | 0x80000000u));
}

#define CSK(a,b) { unsigned h_ = (a) > (b) ? (a) : (b); unsigned l_ = (a) > (b) ? (b) : (a); (a) = h_; (b) = l_; }
#define INSKEY(x_) if ((x_) > t_k11){ t_k11 = (x_); \
    CSK(t_k10,t_k11) CSK(t_k9,t_k10) CSK(t_k8,t_k9) CSK(t_k7,t_k8) \
    CSK(t_k6,t_k7) CSK(t_k5,t_k6) CSK(t_k4,t_k5) CSK(t_k3,t_k4) \
    CSK(t_k2,t_k3) CSK(t_k1,t_k2) CSK(t_k0,t_k1) }

#define KQ(A,Q) { \
    unsigned q0_ = (f2mono(A[4*(Q)+0]) & 0xFFFFF000u) | (unsigned)(jinvb_ - 8*(Q)    ); \
    unsigned q1_ = (f2mono(A[4*(Q)+1]) & 0xFFFFF000u) | (unsigned)(jinvb_ - 8*(Q) - 1); \
    unsigned q2_ = (f2mono(A[4*(Q)+2]) & 0xFFFFF000u) | (unsigned)(jinvb_ - 8*(Q) - 2); \
    unsigned q3_ = (f2mono(A[4*(Q)+3]) & 0xFFFFF000u) | (unsigned)(jinvb_ - 8*(Q) - 3); \
    unsigned qa_ = q0_ > q1_ ? q0_ : q1_; \
    unsigned qb_ = q2_ > q3_ ? q2_ : q3_; \
    unsigned qm_ = qa_ > qb_ ? qa_ : qb_; \
    if (qm_ > t_k11){ INSKEY(q0_) INSKEY(q1_) INSKEY(q2_) INSKEY(q3_) } }

#define AMAX16(A) fmaxf(fmaxf(fmaxf(fmaxf(A[0],A[1]),fmaxf(A[2],A[3])),fmaxf(fmaxf(A[4],A[5]),fmaxf(A[6],A[7]))), \
                        fmaxf(fmaxf(fmaxf(A[8],A[9]),fmaxf(A[10],A[11])),fmaxf(fmaxf(A[12],A[13]),fmaxf(A[14],A[15]))))

#define INSACCK(A,JS) { float am_ = AMAX16(A); \
    if (am_ >= thrf){ int jinvb_ = 4095 - (jg + (JS)*32 + 4*h); \
        KQ(A,0) KQ(A,1) KQ(A,2) KQ(A,3) } }

#define MF(ACC,AO,BO) ACC = __builtin_amdgcn_mfma_f32_32x32x16_f16(AO,BO,ACC,0,0,0);
#define ZERO16 {0,0,0,0,0,0,0,0,0,0,0,0,0,0,0,0}

// ---------------------------------------------------------------------------
// wt: W1,W2 fp32 -> transposed [K][192] fp32 (for FMA ll2). 32x32 LDS tiles.
// ---------------------------------------------------------------------------
__global__ __launch_bounds__(256) void wt_kernel(
    const float* __restrict__ W1, const float* __restrict__ W2,
    float* __restrict__ W1T, float* __restrict__ W2T)
{
    __shared__ float tile[32*33];
    int t = blockIdx.x;
    const float* src; float* dst;
    if (t < 36){ src = W1; dst = W1T; } else { src = W2; dst = W2T; t -= 36; }
    int tr = t / 6, tc = t - tr*6;
    int tid = threadIdx.x;
    {
        int i = tid >> 3, j4 = (tid & 7)*4;
        float4 v = *(const float4*)&src[(size_t)(tr*32 + i)*192 + tc*32 + j4];
        tile[i*33 + j4+0] = v.x; tile[i*33 + j4+1] = v.y;
        tile[i*33 + j4+2] = v.z; tile[i*33 + j4+3] = v.w;
    }
    __syncthreads();
    {
        int j = tid >> 3, i4 = (tid & 7)*4;
        float4 o = make_float4(tile[(i4+0)*33 + j], tile[(i4+1)*33 + j],
                               tile[(i4+2)*33 + j], tile[(i4+3)*33 + j]);
        *(float4*)&dst[(size_t)(tc*32 + j)*192 + tr*32 + i4] = o;
    }
}

// ---------------------------------------------------------------------------
// wt16: Wg,W3,W4 fp32 -> fp16 hi/lo concat [Wg|W3|W4], row-major [n][K].
// ---------------------------------------------------------------------------
__global__ __launch_bounds__(256) void wt16_kernel(
    const float* __restrict__ Wg, const float* __restrict__ W3,
    const float* __restrict__ W4,
    unsigned short* __restrict__ Wh, unsigned short* __restrict__ Wl)
{
    int i = blockIdx.x*256 + threadIdx.x;
    if (i >= 147456) return;
    const float* src; int off;
    if (i < 73728)       { src = Wg; off = i; }
    else if (i < 110592) { src = W3; off = i - 73728; }
    else                 { src = W4; off = i - 110592; }
    float w = src[off];
    _Float16 hi = (_Float16)w;
    Wh[i] = h2u(hi);
    Wl[i] = h2u((_Float16)(w - (float)hi));
}

// ---------------------------------------------------------------------------
// pad: Xh pad rows = 0, S2h pad = fp16(-30000).
// ---------------------------------------------------------------------------
__global__ __launch_bounds__(256) void pad_kernel(
    unsigned short* __restrict__ Xh, unsigned short* __restrict__ S2h)
{
    const int b = blockIdx.x;
    const int tid = threadIdx.x;
    uint4 z = make_uint4(0,0,0,0);
    for (int e = tid; e < 1536; e += 256){
        int r = e / 24, c8 = (e % 24) * 8;
        *(uint4*)&Xh[((size_t)b*NPAD + NPIX + r)*192 + c8] = z;
    }
    if (tid < 64){
        union { _Float16 f; unsigned short u; } p;
        p.f = (_Float16)(-30000.0f);
        S2h[(size_t)b*NPAD + NPIX + tid] = p.u;
    }
}

// ---------------------------------------------------------------------------
// FMA lorentz_linear (R17-proven), col-major activations.
// ---------------------------------------------------------------------------
template<int K, bool WCM, bool DUAL, bool AX, bool CONVF>
__global__ __launch_bounds__(256, 4) void ll2_kernel(
    const float* __restrict__ A0, const float* __restrict__ A1,
    const float* __restrict__ WT, const float* __restrict__ bias,
    const float* __restrict__ sptr, const float* __restrict__ Xres,
    float* __restrict__ OutCM, float* __restrict__ Hrm,
    unsigned short* __restrict__ Xh, unsigned short* __restrict__ S2h,
    float* __restrict__ SQf)
{
    __shared__ float lA[32*36];
    __shared__ float lW[32*196];

    const int tid = threadIdx.x;
    const int tx = tid & 15, ty = tid >> 4;
    const int bid = blockIdx.x;
    const int b  = bid / NMT;
    const int n0 = (bid % NMT) * 32;

    float acc[2][12];
    #pragma unroll
    for (int mi = 0; mi < 2; ++mi)
        #pragma unroll
        for (int j = 0; j < 12; ++j) acc[mi][j] = 0.f;

    for (int kt = 0; kt < K/32; ++kt){
        {
            int kk = tid >> 3;
            int m4 = (tid & 7) * 4;
            int c  = kt*32 + kk;
            const float* pl;
            if (K > 192 && c >= 192) pl = A1 + ((size_t)b*192 + (c - 192))*NPIX;
            else                     pl = A0 + ((size_t)b*192 + c)*NPIX;
            float4 v = *(const float4*)&pl[n0 + m4];
            v.x = gelu_f(v.x); v.y = gelu_f(v.y); v.z = gelu_f(v.z); v.w = gelu_f(v.w);
            *(float4*)&lA[kk*36 + m4] = v;
        }
        #pragma unroll
        for (int r = 0; r < 6; ++r){
            int e  = tid + r*256;
            int kk = e / 48;
            int c4 = (e - kk*48) * 4;
            float4 v = *(const float4*)&WT[(size_t)(kt*32 + kk)*192 + c4];
            *(float4*)&lW[kk*196 + c4] = v;
        }
        __syncthreads();
        #pragma unroll
        for (int kk = 0; kk < 32; ++kk){
            float2 a2 = *(const float2*)&lA[kk*36 + ty*2];
            float4 w0 = *(const float4*)&lW[kk*196 + tx*12];
            float4 w1 = *(const float4*)&lW[kk*196 + tx*12 + 4];
            float4 w2 = *(const float4*)&lW[kk*196 + tx*12 + 8];
            float aw[2]  = {a2.x, a2.y};
            float wv[12] = {w0.x,w0.y,w0.z,w0.w, w1.x,w1.y,w1.z,w1.w, w2.x,w2.y,w2.z,w2.w};
            #pragma unroll
            for (int mi = 0; mi < 2; ++mi)
                #pragma unroll
                for (int j = 0; j < 12; ++j)
                    acc[mi][j] = fmaf(aw[mi], wv[j], acc[mi][j]);
        }
        __syncthreads();
    }

    const int lane = tid & 63;
    float es = expf(sptr[0]);
    float bv[12];
    #pragma unroll
    for (int q = 0; q < 3; ++q){
        float4 t4 = *(const float4*)&bias[tx*12 + q*4];
        bv[q*4+0] = t4.x; bv[q*4+1] = t4.y; bv[q*4+2] = t4.z; bv[q*4+3] = t4.w;
    }
    #pragma unroll
    for (int mi = 0; mi < 2; ++mi){
        float part = 0.f;
        #pragma unroll
        for (int j = 0; j < 12; ++j){
            float y = acc[mi][j] + bv[j];
            acc[mi][j] = y;
            if (!(tx == 0 && j == 0)) part += y * y;
        }
        #pragma unroll
        for (int m = 1; m < 16; m <<= 1) part += __shfl_xor(part, m, 64);
        float y0   = __shfl(acc[mi][0], lane & 48, 64);
        float tval = es / (1.f + expf(-y0)) + 1.1f;
        float denom = fmaxf(part, 1e-8f);
        float sca  = (tval*tval - 1.f) / denom;
        float sqs  = sqrtf(sca);
        #pragma unroll
        for (int j = 0; j < 12; ++j){
            float o = acc[mi][j] * sqs;
            if (tx == 0 && j == 0) o = tval;
            acc[mi][j] = o;
        }
    }
    if (AX){
        #pragma unroll
        for (int j = 0; j < 12; ++j){
            int c = tx*12 + j;
            float2 xv = *(const float2*)&Xres[((size_t)b*192 + c)*NPIX + n0 + ty*2];
            acc[0][j] += xv.x; acc[1][j] += xv.y;
        }
    }
    if (WCM){
        #pragma unroll
        for (int j = 0; j < 12; ++j){
            int c = tx*12 + j;
            *(float2*)&OutCM[((size_t)b*192 + c)*NPIX + n0 + ty*2] = make_float2(acc[0][j], acc[1][j]);
        }
    }
    if (DUAL){
        #pragma unroll
        for (int mi = 0; mi < 2; ++mi){
            #pragma unroll
            for (int q = 0; q < 3; ++q){
                float4 o = make_float4(acc[mi][q*4+0], acc[mi][q*4+1], acc[mi][q*4+2], acc[mi][q*4+3]);
                *(float4*)&Hrm[((size_t)b*NPIX + n0 + ty*2 + mi)*192 + tx*12 + q*4] = o;
            }
        }
    }
    if (CONVF){
        #pragma unroll
        for (int mi = 0; mi < 2; ++mi){
            int row = n0 + ty*2 + mi;
            float s = 0.f;
            #pragma unroll
            for (int j = 0; j < 12; ++j) s = fmaf(acc[mi][j], acc[mi][j], s);
            #pragma unroll
            for (int m = 1; m < 16; m <<= 1) s += __shfl_xor(s, m, 64);
            #pragma unroll
            for (int q = 0; q < 3; ++q){
                uint2 hv;
                hv.x = pack_hi(acc[mi][q*4+0], acc[mi][q*4+1]);
                hv.y = pack_hi(acc[mi][q*4+2], acc[mi][q*4+3]);
                *(uint2*)&Xh[((size_t)b*NPAD + row)*192 + tx*12 + q*4] = hv;
            }
            if (tx == 0){
                SQf[(size_t)b*NPIX + row] = s;
                S2h[(size_t)b*NPAD + row] = h2u((_Float16)(-0.5f * s));
            }
        }
    }
}

// ---------------------------------------------------------------------------
// Fused MFMA chain LLg->LL3->LL4, SINGLE shared tile (25.9 KB LDS).
// Stage-1 outputs kept in regs (xa0/xa1) for LL4's X2f residual.
// ---------------------------------------------------------------------------
#define MLL_EPI(O0,O1,ACC0,ACC1,BIAS,SPTR) { \
    const float es_ = expf((SPTR)[0]); \
    const float bv0_ = (BIAS)[c0], bv1_ = (BIAS)[c1]; \
    float p_[16]; \
    _Pragma("unroll") for (int r = 0; r < 16; ++r){ \
        O0[r] = ACC0[r] + bv0_; O1[r] = ACC1[r] + bv1_; \
        p_[r] = O0[r]*O0[r] + O1[r]*O1[r]; } \
    _Pragma("unroll") for (int m_ = 1; m_ < 32; m_ <<= 1){ \
        _Pragma("unroll") for (int r = 0; r < 16; ++r) p_[r] += __shfl_xor(p_[r], m_, 64); } \
    if (l31 == 0){ \
        _Pragma("unroll") for (int r = 0; r < 16; ++r){ \
            int row = (r&3) + 8*(r>>2) + 4*h; \
            float v = p_[r]; \
            if (w == 0){ v -= O0[r]*O0[r]; y0v[row] = O0[r]; } \
            psum[w][row] = v; } } \
    __syncthreads(); \
    _Pragma("unroll") for (int r = 0; r < 16; ++r){ \
        int row = (r&3) + 8*(r>>2) + 4*h; \
        float S_ = psum[0][row] + psum[1][row] + psum[2][row]; \
        float y0_ = y0v[row]; \
        float tv_ = es_ / (1.f + expf(-y0_)) + 1.1f; \
        float dn_ = fmaxf(S_, 1e-8f); \
        float sq_ = sqrtf((tv_*tv_ - 1.f)/dn_); \
        O0[r] *= sq_; O1[r] *= sq_; \
        if (w == 0 && l31 == 0) O0[r] = tv_; } \
    __syncthreads(); }

#define GSPLIT8(SRC,AH,AL) { \
    _Pragma("unroll") for (int e_ = 0; e_ < 8; ++e_){ \
        float gg_ = gelu_f((SRC)[e_]); \
        _Float16 hi_ = (_Float16)gg_; \
        AH[e_] = hi_; AL[e_] = (_Float16)(gg_ - (float)hi_); } }

__global__ __launch_bounds__(192) void mfuse_kernel(
    const float* __restrict__ Hrm, const float* __restrict__ Msg,
    const unsigned short* __restrict__ Wgh, const unsigned short* __restrict__ Wgl,
    const unsigned short* __restrict__ W3h, const unsigned short* __restrict__ W3l,
    const unsigned short* __restrict__ W4h, const unsigned short* __restrict__ W4l,
    const float* __restrict__ bg, const float* __restrict__ sg,
    const float* __restrict__ b3, const float* __restrict__ s3,
    const float* __restrict__ b4, const float* __restrict__ s4,
    const float* __restrict__ x, float* __restrict__ out)
{
    __shared__ float psum[3][32], y0v[32];
    __shared__ float tile[32*198];

    const int tid = threadIdx.x;
    const int w = tid >> 6, lane = tid & 63, l31 = lane & 31, h = lane >> 5;
    const int bid = blockIdx.x;
    const int b = bid / NMT, mt = bid % NMT;
    const int row0 = mt*32;
    const int nb = w*64;
    const size_t arow = (size_t)b*NPIX + row0 + l31;
    const int c0 = nb + l31, c1 = nb + 32 + l31;

    float o0[16], o1[16];
    float xa0[16], xa1[16];   // stage-1 outputs (X2f) kept for LL4 residual

    // ---------------- Stage 1: LLg (K=384, A = gelu(Hrm|Msg)) ----------------
    {
        f32x16 acc0 = ZERO16, acc1 = ZERO16;
        #pragma unroll
        for (int ks = 0; ks < 24; ++ks){
            const int kb = ks*16 + h*8;
            const float* src = (ks < 12) ? (Hrm + arow*192 + kb) : (Msg + arow*192 + (kb - 192));
            float g[8];
            *(float4*)&g[0] = *(const float4*)src;
            *(float4*)&g[4] = *(const float4*)(src + 4);
            f16x8 ah, al;
            GSPLIT8(g, ah, al)
            f16x8 wh0 = __builtin_bit_cast(f16x8, *(const uint4*)&Wgh[(size_t)c0*384 + kb]);
            f16x8 wl0 = __builtin_bit_cast(f16x8, *(const uint4*)&Wgl[(size_t)c0*384 + kb]);
            f16x8 wh1 = __builtin_bit_cast(f16x8, *(const uint4*)&Wgh[(size_t)c1*384 + kb]);
            f16x8 wl1 = __builtin_bit_cast(f16x8, *(const uint4*)&Wgl[(size_t)c1*384 + kb]);
            MF(acc0, ah, wh0) MF(acc0, al, wh0) MF(acc0, ah, wl0)
            MF(acc1, ah, wh1) MF(acc1, al, wh1) MF(acc1, ah, wl1)
        }
        MLL_EPI(o0, o1, acc0, acc1, bg, sg)
        #pragma unroll
        for (int r = 0; r < 16; ++r){
            int row = (r&3) + 8*(r>>2) + 4*h;
            tile[row*198 + c0] = o0[r];
            tile[row*198 + c1] = o1[r];
            xa0[r] = o0[r];
            xa1[r] = o1[r];
        }
        __syncthreads();
    }

    // ---------------- Stage 2: LL3 (K=192, A = gelu(tile)) ----------------
    {
        f32x16 acc0 = ZERO16, acc1 = ZERO16;
        #pragma unroll
        for (int ks = 0; ks < 12; ++ks){
            const int kb = ks*16 + h*8;
            float g[8];
            #pragma unroll
            for (int e = 0; e < 8; ++e) g[e] = tile[l31*198 + kb + e];
            f16x8 ah, al;
            GSPLIT8(g, ah, al)
            f16x8 wh0 = __builtin_bit_cast(f16x8, *(const uint4*)&W3h[(size_t)c0*192 + kb]);
            f16x8 wl0 = __builtin_bit_cast(f16x8, *(const uint4*)&W3l[(size_t)c0*192 + kb]);
            f16x8 wh1 = __builtin_bit_cast(f16x8, *(const uint4*)&W3h[(size_t)c1*192 + kb]);
            f16x8 wl1 = __builtin_bit_cast(f16x8, *(const uint4*)&W3l[(size_t)c1*192 + kb]);
            MF(acc0, ah, wh0) MF(acc0, al, wh0) MF(acc0, ah, wl0)
            MF(acc1, ah, wh1) MF(acc1, al, wh1) MF(acc1, ah, wl1)
        }
        MLL_EPI(o0, o1, acc0, acc1, b3, s3)
        // overwrite the single tile (all tile reads completed before MLL_EPI's barrier)
        #pragma unroll
        for (int r = 0; r < 16; ++r){
            int row = (r&3) + 8*(r>>2) + 4*h;
            tile[row*198 + c0] = o0[r];
            tile[row*198 + c1] = o1[r];
        }
        __syncthreads();
    }

    // ---------------- Stage 3: LL4 (K=192, A = gelu(tile)) ----------------
    {
        f32x16 acc0 = ZERO16, acc1 = ZERO16;
        #pragma unroll
        for (int ks = 0; ks < 12; ++ks){
            const int kb = ks*16 + h*8;
            float g[8];
            #pragma unroll
            for (int e = 0; e < 8; ++e) g[e] = tile[l31*198 + kb + e];
            f16x8 ah, al;
            GSPLIT8(g, ah, al)
            f16x8 wh0 = __builtin_bit_cast(f16x8, *(const uint4*)&W4h[(size_t)c0*192 + kb]);
            f16x8 wl0 = __builtin_bit_cast(f16x8, *(const uint4*)&W4l[(size_t)c0*192 + kb]);
            f16x8 wh1 = __builtin_bit_cast(f16x8, *(const uint4*)&W4h[(size_t)c1*192 + kb]);
            f16x8 wl1 = __builtin_bit_cast(f16x8, *(const uint4*)&W4l[(size_t)c1*192 + kb]);
            MF(acc0, ah, wh0) MF(acc0, al, wh0) MF(acc0, ah, wl0)
            MF(acc1, ah, wh1) MF(acc1, al, wh1) MF(acc1, ah, wl1)
        }
        MLL_EPI(o0, o1, acc0, acc1, b4, s4)
        // residuals: X2f (registers) + x (global col-major)
        #pragma unroll
        for (int r = 0; r < 16; ++r){ o0[r] += xa0[r]; o1[r] += xa1[r]; }
        #pragma unroll
        for (int p4 = 0; p4 < 4; ++p4){
            float4 xv0 = *(const float4*)&x[((size_t)b*192 + c0)*NPIX + row0 + 8*p4 + 4*h];
            float4 xv1 = *(const float4*)&x[((size_t)b*192 + c1)*NPIX + row0 + 8*p4 + 4*h];
            o0[4*p4+0] += xv0.x; o0[4*p4+1] += xv0.y; o0[4*p4+2] += xv0.z; o0[4*p4+3] += xv0.w;
            o1[4*p4+0] += xv1.x; o1[4*p4+1] += xv1.y; o1[4*p4+2] += xv1.z; o1[4*p4+3] += xv1.w;
        }
        #pragma unroll
        for (int p4 = 0; p4 < 4; ++p4){
            *(float4*)&out[((size_t)b*192 + c0)*NPIX + row0 + 8*p4 + 4*h] =
                make_float4(o0[4*p4+0], o0[4*p4+1], o0[4*p4+2], o0[4*p4+3]);
            *(float4*)&out[((size_t)b*192 + c1)*NPIX + row0 + 8*p4 + 4*h] =
                make_float4(o1[4*p4+0], o1[4*p4+1], o1[4*p4+2], o1[4*p4+3]);
        }
    }
}

// ---------------------------------------------------------------------------
// MFMA kNN screen (R21 double-buffered version).
// ---------------------------------------------------------------------------
__global__ __launch_bounds__(256) __attribute__((amdgpu_waves_per_eu(2))) void knn_kernel(
    const unsigned short* __restrict__ Xh, const unsigned short* __restrict__ S2h,
    unsigned* __restrict__ PK)
{
    __shared__ uint4 lds[2][640];

    const int tid  = threadIdx.x;
    const int lane = tid & 63;
    const int w    = tid >> 6;
    const int l31  = lane & 31;
    const int h    = lane >> 5;
    const int bid  = blockIdx.x;
    const int b    = bid & 7;
    const int t2   = bid >> 3;
    const int itile = t2 >> 3;
    const int sp    = t2 & 7;
    const int i0    = itile * 128;
    const int g0 = (sp*25)/NSP, g1 = ((sp+1)*25)/NSP;
    const size_t rowb = (size_t)b * NPAD;

    const size_t bbase = (rowb + i0 + w*32 + l31)*192;
    f16x8 B[6][2];
    #pragma unroll
    for (int kc = 0; kc < 6; ++kc)
        #pragma unroll
        for (int ks = 0; ks < 2; ++ks)
            B[kc][ks] = __builtin_bit_cast(f16x8, *(const uint4*)&Xh[bbase + kc*32 + (ks*2 + h)*8]);

    unsigned t_k0=0,t_k1=0,t_k2=0,t_k3=0,t_k4=0,t_k5=0,
             t_k6=0,t_k7=0,t_k8=0,t_k9=0,t_k10=0,t_k11=0;
    float thrf = -FINF;

    const int rs0 = tid >> 2, seg0 = tid & 3;
    const int wr0 = rs0*5 + seg0, wr1 = (rs0 + 64)*5 + seg0;

    uint4 pv0 = *(const uint4*)&Xh[(rowb + g0*128 + rs0)*192 + seg0*8];
    uint4 pv1 = *(const uint4*)&Xh[(rowb + g0*128 + rs0 + 64)*192 + seg0*8];

    for (int g = g0; g < g1; ++g){
        const int jg = g*128;
        f32x16 acc0 = ZERO16, acc1 = ZERO16, acc2 = ZERO16, acc3 = ZERO16;

        #pragma unroll
        for (int kc = 0; kc < 6; ++kc){
            const int buf = kc & 1;
            lds[buf][wr0] = pv0;
            lds[buf][wr1] = pv1;
            {
                int nkc = (kc < 5) ? kc + 1 : 0;
                int njg = (kc < 5) ? jg : jg + 128;
                if (kc < 5 || g + 1 < g1){
                    pv0 = *(const uint4*)&Xh[(rowb + njg + rs0)*192 + nkc*32 + seg0*8];
                    pv1 = *(const uint4*)&Xh[(rowb + njg + rs0 + 64)*192 + nkc*32 + seg0*8];
                }
            }
            __syncthreads();
            #pragma unroll
            for (int ks = 0; ks < 2; ++ks){
                int rb = l31*5 + (ks*2 + h);
                f16x8 bh = B[kc][ks];
                f16x8 a0h = __builtin_bit_cast(f16x8, lds[buf][  0 + rb]);
                f16x8 a1h = __builtin_bit_cast(f16x8, lds[buf][160 + rb]);
                f16x8 a2h = __builtin_bit_cast(f16x8, lds[buf][320 + rb]);
                f16x8 a3h = __builtin_bit_cast(f16x8, lds[buf][480 + rb]);
                MF(acc0, a0h, bh)
                MF(acc1, a1h, bh)
                MF(acc2, a2h, bh)
                MF(acc3, a3h, bh)
            }
        }

        {
            unsigned m  = (h == 0) ? 0xFFFFFFFFu : 0u;
            unsigned om = 0x3C00u & m;
            f16x8 one = __builtin_bit_cast(f16x8, make_uint4(om, 0, 0, 0));
            unsigned s0 = (unsigned)S2h[rowb + jg +  0 + l31];
            unsigned s1 = (unsigned)S2h[rowb + jg + 32 + l31];
            unsigned s2 = (unsigned)S2h[rowb + jg + 64 + l31];
            unsigned s3 = (unsigned)S2h[rowb + jg + 96 + l31];
            f16x8 a;
            a = __builtin_bit_cast(f16x8, make_uint4(s0 & m, 0,0,0)); MF(acc0, a, one)
            a = __builtin_bit_cast(f16x8, make_uint4(s1 & m, 0,0,0)); MF(acc1, a, one)
            a = __builtin_bit_cast(f16x8, make_uint4(s2 & m, 0,0,0)); MF(acc2, a, one)
            a = __builtin_bit_cast(f16x8, make_uint4(s3 & m, 0,0,0)); MF(acc3, a, one)
        }

        INSACCK(acc0, 0)
        INSACCK(acc1, 1)
        INSACCK(acc2, 2)
        INSACCK(acc3, 3)
        thrf = (t_k11 != 0u) ? unmono(t_k11 & 0xFFFFF000u) : -FINF;
    }

    #define MRGK(Kk) { unsigned ok_ = __shfl((int)(Kk), lane ^ 32, 64); \
                      if (lane < 32) { INSKEY((unsigned)ok_) } }
    MRGK(t_k0) MRGK(t_k1) MRGK(t_k2) MRGK(t_k3) MRGK(t_k4) MRGK(t_k5)
    MRGK(t_k6) MRGK(t_k7) MRGK(t_k8) MRGK(t_k9) MRGK(t_k10) MRGK(t_k11)

    if (lane < 32){
        size_t po = ((size_t)(t2*8 + b)*128 + (size_t)w*32 + l31)*12;
        PK[po+ 0] = t_k0;  PK[po+ 1] = t_k1;  PK[po+ 2] = t_k2;  PK[po+ 3] = t_k3;
        PK[po+ 4] = t_k4;  PK[po+ 5] = t_k5;  PK[po+ 6] = t_k6;  PK[po+ 7] = t_k7;
        PK[po+ 8] = t_k8;  PK[po+ 9] = t_k9;  PK[po+10] = t_k10; PK[po+11] = t_k11;
    }
}

// ---------------------------------------------------------------------------
// 8-way key merge -> approx top-16 -> exact fp32 rescore -> top-9
// -> max-message, Msg fp32 ROW-MAJOR [m][192].
// ---------------------------------------------------------------------------
__global__ __launch_bounds__(256) void merge_msg_kernel(
    const float* __restrict__ H, const float* __restrict__ SQf,
    const unsigned* __restrict__ PK, float* __restrict__ Msg)
{
    __shared__ float liX[16*196];
    __shared__ unsigned kv[1600];
    __shared__ float cd[256];
    __shared__ int   cidx[256];
    __shared__ int   fidx[144];

    const int tid = threadIdx.x;
    const int bid = blockIdx.x;
    const int b  = bid / 196;
    const int i0 = (bid % 196) * 16;
    const int base = b * NPIX;

    #pragma unroll
    for (int k = 0; k < 3; ++k){
        int f = tid + k*256;
        int r = f / 48, c4 = f % 48;
        *(float4*)&liX[r*196 + c4*4] = *(const float4*)&H[(size_t)(base + i0 + r)*192 + c4*4];
    }
    if (tid < 128){
        int r = tid >> 3, sp = tid & 7;
        int i = i0 + r;
        size_t po = ((size_t)(((i>>7)*NSP + sp)*8 + b)*128 + (i & 127))*12;
        #pragma unroll
        for (int q = 0; q < 3; ++q)
            *(uint4*)&kv[r*100 + sp*12 + q*4] = *(const uint4*)&PK[po + q*4];
    }
    __syncthreads();

    if (tid < 16){
        int r = tid;
        int h0=0,h1=0,h2=0,h3=0,h4=0,h5=0,h6=0,h7=0;
        #pragma unroll
        for (int p = 0; p < 16; ++p){
            unsigned bk = 0; int bs = 0;
#define HEADC(SP,HV) { \
            unsigned k_ = (HV < 12) ? kv[r*100 + SP*12 + HV] : 0u; \
            bool bt_ = k_ > bk; \
            bk = bt_? k_ : bk; bs = bt_? SP : bs; }
            HEADC(0,h0) HEADC(1,h1) HEADC(2,h2) HEADC(3,h3)
            HEADC(4,h4) HEADC(5,h5) HEADC(6,h6) HEADC(7,h7)
#undef HEADC
            cidx[r*16 + p] = 4095 - (int)(bk & 0xFFFu);
            h0 += (bs==0); h1 += (bs==1); h2 += (bs==2); h3 += (bs==3);
            h4 += (bs==4); h5 += (bs==5); h6 += (bs==6); h7 += (bs==7);
        }
    }
    __syncthreads();

    {
        int r = tid >> 4, p = tid & 15;
        int j = cidx[r*16 + p];
        const float* hj = &H[(size_t)(base + j)*192];
        float dot = 0.f;
        #pragma unroll
        for (int q = 0; q < 48; ++q){
            float4 xv = *(const float4*)&liX[r*196 + q*4];
            float4 yv = *(const float4*)&hj[q*4];
            dot = fmaf(xv.x,yv.x, fmaf(xv.y,yv.y, fmaf(xv.z,yv.z, fmaf(xv.w,yv.w, dot))));
        }
        cd[r*16 + p] = SQf[base + j] - 2.f*dot;
    }
    __syncthreads();

    if (tid < 16){
        int r = tid;
        Top9 m; m.init();
        #pragma unroll
        for (int c = 0; c < 16; ++c) m.insert(cd[r*16 + c], cidx[r*16 + c]);
        fidx[r*9+0]=m.j0; fidx[r*9+1]=m.j1; fidx[r*9+2]=m.j2; fidx[r*9+3]=m.j3;
        fidx[r*9+4]=m.j4; fidx[r*9+5]=m.j5; fidx[r*9+6]=m.j6; fidx[r*9+7]=m.j7;
        fidx[r*9+8]=m.j8;
    }
    __syncthreads();

    int rr = tid >> 4, part = tid & 15;
    int ii = i0 + rr;
    int nbr[9];
    #pragma unroll
    for (int e = 0; e < 9; ++e) nbr[e] = fidx[rr*9 + e];
    #pragma unroll
    for (int q = 0; q < 3; ++q){
        float4 mv = make_float4(-FINF, -FINF, -FINF, -FINF);
        #pragma unroll
        for (int e = 0; e < 9; ++e){
            float4 v = *(const float4*)&H[(size_t)(base + nbr[e])*192 + part*12 + q*4];
            mv.x = fmaxf(mv.x, v.x); mv.y = fmaxf(mv.y, v.y);
            mv.z = fmaxf(mv.z, v.z); mv.w = fmaxf(mv.w, v.w);
        }
        float4 xi = *(const float4*)&liX[rr*196 + part*12 + q*4];
        *(float4*)&Msg[(size_t)(base + ii)*192 + part*12 + q*4] =
            make_float4(mv.x - xi.x, mv.y - xi.y, mv.z - xi.z, mv.w - xi.w);
    }
}

extern "C" void kernel_launch(void* const* d_in, const int* in_sizes, int n_in,
                              void* d_out, int out_size, void* d_ws, size_t ws_size,
                              hipStream_t stream)
{
    const float* x  = (const float*)d_in[0];
    const float* W1 = (const float*)d_in[1];
    const float* b1 = (const float*)d_in[2];
    const float* s1 = (const float*)d_in[3];
    const float* W2 = (const float*)d_in[4];
    const float* b2 = (const float*)d_in[5];
    const float* s2 = (const float*)d_in[6];
    const float* Wg = (const float*)d_in[7];
    const float* bg = (const float*)d_in[8];
    const float* sg = (const float*)d_in[9];
    const float* W3 = (const float*)d_in[10];
    const float* b3 = (const float*)d_in[11];
    const float* s3 = (const float*)d_in[12];
    const float* W4 = (const float*)d_in[13];
    const float* b4 = (const float*)d_in[14];
    const float* s4 = (const float*)d_in[15];
    float* ws = (float*)d_ws;
    float* out = (float*)d_out;

    const size_t NE = (size_t)NB*NPIX*192;
    float* T1cm = ws;
    float* Msg  = ws;
    float* Hrm  = ws + NE;
    unsigned short* Xh  = (unsigned short*)(ws + 3*NE);
    unsigned short* S2h = Xh + (size_t)NB*NPAD*192;
    float* SQf = (float*)(S2h + (size_t)NB*NPAD);
    unsigned* PK = (unsigned*)(SQf + (size_t)NB*NPIX);
    float* W1T = (float*)(PK + (size_t)GRID_KNN*128*12);
    float* W2T = W1T + 36864;
    unsigned short* Wh16 = (unsigned short*)(W2T + 36864);
    unsigned short* Wl16 = Wh16 + 147456;
    const unsigned short* Wgh = Wh16,          *Wgl = Wl16;
    const unsigned short* W3h = Wh16 + 73728,  *W3l = Wl16 + 73728;
    const unsigned short* W4h = Wh16 + 110592, *W4l = Wl16 + 110592;

    wt_kernel<<<72, 256, 0, stream>>>(W1, W2, W1T, W2T);
    wt16_kernel<<<576, 256, 0, stream>>>(Wg, W3, W4, Wh16, Wl16);
    pad_kernel<<<NB, 256, 0, stream>>>(Xh, S2h);
    // LL1 (FMA): x -> T1cm
    ll2_kernel<192, true , false, false, false><<<GRID_LL, 256, 0, stream>>>(
        x, x, W1T, b1, s1, nullptr, T1cm, nullptr, nullptr, nullptr, nullptr);
    // LL2 (FMA): T1cm -> Hrm (+x residual) + conv outputs
    ll2_kernel<192, false, true , true , true ><<<GRID_LL, 256, 0, stream>>>(
        T1cm, T1cm, W2T, b2, s2, x, nullptr, Hrm, Xh, S2h, SQf);
    // graph conv
    knn_kernel<<<GRID_KNN, 256, 0, stream>>>(Xh, S2h, PK);
    merge_msg_kernel<<<GRID_MSG, 256, 0, stream>>>(Hrm, SQf, PK, Msg);
    // fused LLg -> LL3 -> LL4 (MFMA), output col-major = (B,C,H,W) native
    mfuse_kernel<<<GRID_LL, 192, 0, stream>>>(
        Hrm, Msg, Wgh, Wgl, W3h, W3l, W4h, W4l,
        bg, sg, b3, s3, b4, s4, x, out);
}

// Round 26
// 424.521 us; speedup vs baseline: 1.0385x; 1.0376x over previous
//
#include <hip/hip_runtime.h>
#include <math.h>

#define NB   8
#define NC   192
#define NPIX 3136
#define NPAD 3200
#define NMT  98
#define GRID_LL (NB*NMT)   // 784
#define NIT  25
#define NSP  8
#define GRID_KNN (NB*NIT*NSP)   // 1600
#define GRID_MSG (NB*196)  // 1568
#define FINF 3.4e38f

typedef _Float16 f16x8 __attribute__((ext_vector_type(8)));
typedef float   f32x16 __attribute__((ext_vector_type(16)));

__device__ __forceinline__ float gelu_f(float x){
    float u = 0.7978845608028654f * (x + 0.044715f * x * x * x);
    return 0.5f * x * (1.0f + tanhf(u));
}
__device__ __forceinline__ unsigned short h2u(_Float16 v){
    union { _Float16 f; unsigned short u; } c; c.f = v; return c.u;
}
__device__ __forceinline__ unsigned pack_hi(float a, float b){
    return (unsigned)h2u((_Float16)a) | ((unsigned)h2u((_Float16)b) << 16);
}

// ---------------- min-lex top9 ----------------
#define LESS9(da,ia,db,ib) ((da) < (db) || ((da) == (db) && (ia) < (ib)))
#define CSW9(a,ia,b,ib) { bool sw_ = LESS9(b,ib,a,ia); float tf_=(a); int ti_=(ia); \
    (a) = sw_? (b) : (a); (ia) = sw_? (ib) : (ia); (b) = sw_? tf_ : (b); (ib) = sw_? ti_ : (ib); }

struct Top9 {
    float d0,d1,d2,d3,d4,d5,d6,d7,d8;
    int   j0,j1,j2,j3,j4,j5,j6,j7,j8;
    __device__ __forceinline__ void init(){
        d0=d1=d2=d3=d4=d5=d6=d7=d8=FINF;
        j0=j1=j2=j3=j4=j5=j6=j7=j8=0x7FFFFFFF;
    }
    __device__ __forceinline__ void insert(float nd, int ni){
        if (!LESS9(nd, ni, d8, j8)) return;
        d8 = nd; j8 = ni;
        CSW9(d7,j7,d8,j8); CSW9(d6,j6,d7,j7); CSW9(d5,j5,d6,j6); CSW9(d4,j4,d5,j5);
        CSW9(d3,j3,d4,j4); CSW9(d2,j2,d3,j3); CSW9(d1,j1,d2,j2); CSW9(d0,j0,d1,j1);
    }
};

// ---------------- u32-key top12 (knn screen) ----------------
__device__ __forceinline__ unsigned f2mono(float e){
    unsigned u = __float_as_uint(e);
    return u ^ ((unsigned)((int)u >> 31) | 0x80000000u);
}
__device__ __forceinline__ float unmono(unsigned m){
    return __uint_as_float(m ^ ((unsigned)(((int)~m) >> 31) | 0x80000000u));
}

#define CSK(a,b) { unsigned h_ = (a) > (b) ? (a) : (b); unsigned l_ = (a) > (b) ? (b) : (a); (a) = h_; (b) = l_; }
#define INSKEY(x_) if ((x_) > t_k11){ t_k11 = (x_); \
    CSK(t_k10,t_k11) CSK(t_k9,t_k10) CSK(t_k8,t_k9) CSK(t_k7,t_k8) \
    CSK(t_k6,t_k7) CSK(t_k5,t_k6) CSK(t_k4,t_k5) CSK(t_k3,t_k4) \
    CSK(t_k2,t_k3) CSK(t_k1,t_k2) CSK(t_k0,t_k1) }

#define KQ(A,Q) { \
    unsigned q0_ = (f2mono(A[4*(Q)+0]) & 0xFFFFF000u) | (unsigned)(jinvb_ - 8*(Q)    ); \
    unsigned q1_ = (f2mono(A[4*(Q)+1]) & 0xFFFFF000u) | (unsigned)(jinvb_ - 8*(Q) - 1); \
    unsigned q2_ = (f2mono(A[4*(Q)+2]) & 0xFFFFF000u) | (unsigned)(jinvb_ - 8*(Q) - 2); \
    unsigned q3_ = (f2mono(A[4*(Q)+3]) & 0xFFFFF000u) | (unsigned)(jinvb_ - 8*(Q) - 3); \
    unsigned qa_ = q0_ > q1_ ? q0_ : q1_; \
    unsigned qb_ = q2_ > q3_ ? q2_ : q3_; \
    unsigned qm_ = qa_ > qb_ ? qa_ : qb_; \
    if (qm_ > t_k11){ INSKEY(q0_) INSKEY(q1_) INSKEY(q2_) INSKEY(q3_) } }

#define AMAX16(A) fmaxf(fmaxf(fmaxf(fmaxf(A[0],A[1]),fmaxf(A[2],A[3])),fmaxf(fmaxf(A[4],A[5]),fmaxf(A[6],A[7]))), \
                        fmaxf(fmaxf(fmaxf(A[8],A[9]),fmaxf(A[10],A[11])),fmaxf(fmaxf(A[12],A[13]),fmaxf(A[14],A[15]))))

#define INSACCK(A,JS) { float am_ = AMAX16(A); \
    if (am_ >= thrf){ int jinvb_ = 4095 - (jg + (JS)*32 + 4*h); \
        KQ(A,0) KQ(A,1) KQ(A,2) KQ(A,3) } }

#define MF(ACC,AO,BO) ACC = __builtin_amdgcn_mfma_f32_32x32x16_f16(AO,BO,ACC,0,0,0);
#define ZERO16 {0,0,0,0,0,0,0,0,0,0,0,0,0,0,0,0}

// ---------------------------------------------------------------------------
// wt: W1,W2 fp32 -> transposed [K][192] fp32 (for FMA ll2). 32x32 LDS tiles.
// ---------------------------------------------------------------------------
__global__ __launch_bounds__(256) void wt_kernel(
    const float* __restrict__ W1, const float* __restrict__ W2,
    float* __restrict__ W1T, float* __restrict__ W2T)
{
    __shared__ float tile[32*33];
    int t = blockIdx.x;
    const float* src; float* dst;
    if (t < 36){ src = W1; dst = W1T; } else { src = W2; dst = W2T; t -= 36; }
    int tr = t / 6, tc = t - tr*6;
    int tid = threadIdx.x;
    {
        int i = tid >> 3, j4 = (tid & 7)*4;
        float4 v = *(const float4*)&src[(size_t)(tr*32 + i)*192 + tc*32 + j4];
        tile[i*33 + j4+0] = v.x; tile[i*33 + j4+1] = v.y;
        tile[i*33 + j4+2] = v.z; tile[i*33 + j4+3] = v.w;
    }
    __syncthreads();
    {
        int j = tid >> 3, i4 = (tid & 7)*4;
        float4 o = make_float4(tile[(i4+0)*33 + j], tile[(i4+1)*33 + j],
                               tile[(i4+2)*33 + j], tile[(i4+3)*33 + j]);
        *(float4*)&dst[(size_t)(tc*32 + j)*192 + tr*32 + i4] = o;
    }
}

// ---------------------------------------------------------------------------
// wt16: Wg,W3,W4 fp32 -> fp16 hi/lo concat [Wg|W3|W4], row-major [n][K].
// ---------------------------------------------------------------------------
__global__ __launch_bounds__(256) void wt16_kernel(
    const float* __restrict__ Wg, const float* __restrict__ W3,
    const float* __restrict__ W4,
    unsigned short* __restrict__ Wh, unsigned short* __restrict__ Wl)
{
    int i = blockIdx.x*256 + threadIdx.x;
    if (i >= 147456) return;
    const float* src; int off;
    if (i < 73728)       { src = Wg; off = i; }
    else if (i < 110592) { src = W3; off = i - 73728; }
    else                 { src = W4; off = i - 110592; }
    float w = src[off];
    _Float16 hi = (_Float16)w;
    Wh[i] = h2u(hi);
    Wl[i] = h2u((_Float16)(w - (float)hi));
}

// ---------------------------------------------------------------------------
// pad: Xh pad rows = 0, S2h pad = fp16(-30000).
// ---------------------------------------------------------------------------
__global__ __launch_bounds__(256) void pad_kernel(
    unsigned short* __restrict__ Xh, unsigned short* __restrict__ S2h)
{
    const int b = blockIdx.x;
    const int tid = threadIdx.x;
    uint4 z = make_uint4(0,0,0,0);
    for (int e = tid; e < 1536; e += 256){
        int r = e / 24, c8 = (e % 24) * 8;
        *(uint4*)&Xh[((size_t)b*NPAD + NPIX + r)*192 + c8] = z;
    }
    if (tid < 64){
        union { _Float16 f; unsigned short u; } p;
        p.f = (_Float16)(-30000.0f);
        S2h[(size_t)b*NPAD + NPIX + tid] = p.u;
    }
}

// ---------------------------------------------------------------------------
// FMA lorentz_linear (R17-proven), col-major activations.
// ---------------------------------------------------------------------------
template<int K, bool WCM, bool DUAL, bool AX, bool CONVF>
__global__ __launch_bounds__(256, 4) void ll2_kernel(
    const float* __restrict__ A0, const float* __restrict__ A1,
    const float* __restrict__ WT, const float* __restrict__ bias,
    const float* __restrict__ sptr, const float* __restrict__ Xres,
    float* __restrict__ OutCM, float* __restrict__ Hrm,
    unsigned short* __restrict__ Xh, unsigned short* __restrict__ S2h,
    float* __restrict__ SQf)
{
    __shared__ float lA[32*36];
    __shared__ float lW[32*196];

    const int tid = threadIdx.x;
    const int tx = tid & 15, ty = tid >> 4;
    const int bid = blockIdx.x;
    const int b  = bid / NMT;
    const int n0 = (bid % NMT) * 32;

    float acc[2][12];
    #pragma unroll
    for (int mi = 0; mi < 2; ++mi)
        #pragma unroll
        for (int j = 0; j < 12; ++j) acc[mi][j] = 0.f;

    for (int kt = 0; kt < K/32; ++kt){
        {
            int kk = tid >> 3;
            int m4 = (tid & 7) * 4;
            int c  = kt*32 + kk;
            const float* pl;
            if (K > 192 && c >= 192) pl = A1 + ((size_t)b*192 + (c - 192))*NPIX;
            else                     pl = A0 + ((size_t)b*192 + c)*NPIX;
            float4 v = *(const float4*)&pl[n0 + m4];
            v.x = gelu_f(v.x); v.y = gelu_f(v.y); v.z = gelu_f(v.z); v.w = gelu_f(v.w);
            *(float4*)&lA[kk*36 + m4] = v;
        }
        #pragma unroll
        for (int r = 0; r < 6; ++r){
            int e  = tid + r*256;
            int kk = e / 48;
            int c4 = (e - kk*48) * 4;
            float4 v = *(const float4*)&WT[(size_t)(kt*32 + kk)*192 + c4];
            *(float4*)&lW[kk*196 + c4] = v;
        }
        __syncthreads();
        #pragma unroll
        for (int kk = 0; kk < 32; ++kk){
            float2 a2 = *(const float2*)&lA[kk*36 + ty*2];
            float4 w0 = *(const float4*)&lW[kk*196 + tx*12];
            float4 w1 = *(const float4*)&lW[kk*196 + tx*12 + 4];
            float4 w2 = *(const float4*)&lW[kk*196 + tx*12 + 8];
            float aw[2]  = {a2.x, a2.y};
            float wv[12] = {w0.x,w0.y,w0.z,w0.w, w1.x,w1.y,w1.z,w1.w, w2.x,w2.y,w2.z,w2.w};
            #pragma unroll
            for (int mi = 0; mi < 2; ++mi)
                #pragma unroll
                for (int j = 0; j < 12; ++j)
                    acc[mi][j] = fmaf(aw[mi], wv[j], acc[mi][j]);
        }
        __syncthreads();
    }

    const int lane = tid & 63;
    float es = expf(sptr[0]);
    float bv[12];
    #pragma unroll
    for (int q = 0; q < 3; ++q){
        float4 t4 = *(const float4*)&bias[tx*12 + q*4];
        bv[q*4+0] = t4.x; bv[q*4+1] = t4.y; bv[q*4+2] = t4.z; bv[q*4+3] = t4.w;
    }
    #pragma unroll
    for (int mi = 0; mi < 2; ++mi){
        float part = 0.f;
        #pragma unroll
        for (int j = 0; j < 12; ++j){
            float y = acc[mi][j] + bv[j];
            acc[mi][j] = y;
            if (!(tx == 0 && j == 0)) part += y * y;
        }
        #pragma unroll
        for (int m = 1; m < 16; m <<= 1) part += __shfl_xor(part, m, 64);
        float y0   = __shfl(acc[mi][0], lane & 48, 64);
        float tval = es / (1.f + expf(-y0)) + 1.1f;
        float denom = fmaxf(part, 1e-8f);
        float sca  = (tval*tval - 1.f) / denom;
        float sqs  = sqrtf(sca);
        #pragma unroll
        for (int j = 0; j < 12; ++j){
            float o = acc[mi][j] * sqs;
            if (tx == 0 && j == 0) o = tval;
            acc[mi][j] = o;
        }
    }
    if (AX){
        #pragma unroll
        for (int j = 0; j < 12; ++j){
            int c = tx*12 + j;
            float2 xv = *(const float2*)&Xres[((size_t)b*192 + c)*NPIX + n0 + ty*2];
            acc[0][j] += xv.x; acc[1][j] += xv.y;
        }
    }
    if (WCM){
        #pragma unroll
        for (int j = 0; j < 12; ++j){
            int c = tx*12 + j;
            *(float2*)&OutCM[((size_t)b*192 + c)*NPIX + n0 + ty*2] = make_float2(acc[0][j], acc[1][j]);
        }
    }
    if (DUAL){
        #pragma unroll
        for (int mi = 0; mi < 2; ++mi){
            #pragma unroll
            for (int q = 0; q < 3; ++q){
                float4 o = make_float4(acc[mi][q*4+0], acc[mi][q*4+1], acc[mi][q*4+2], acc[mi][q*4+3]);
                *(float4*)&Hrm[((size_t)b*NPIX + n0 + ty*2 + mi)*192 + tx*12 + q*4] = o;
            }
        }
    }
    if (CONVF){
        #pragma unroll
        for (int mi = 0; mi < 2; ++mi){
            int row = n0 + ty*2 + mi;
            float s = 0.f;
            #pragma unroll
            for (int j = 0; j < 12; ++j) s = fmaf(acc[mi][j], acc[mi][j], s);
            #pragma unroll
            for (int m = 1; m < 16; m <<= 1) s += __shfl_xor(s, m, 64);
            #pragma unroll
            for (int q = 0; q < 3; ++q){
                uint2 hv;
                hv.x = pack_hi(acc[mi][q*4+0], acc[mi][q*4+1]);
                hv.y = pack_hi(acc[mi][q*4+2], acc[mi][q*4+3]);
                *(uint2*)&Xh[((size_t)b*NPAD + row)*192 + tx*12 + q*4] = hv;
            }
            if (tx == 0){
                SQf[(size_t)b*NPIX + row] = s;
                S2h[(size_t)b*NPAD + row] = h2u((_Float16)(-0.5f * s));
            }
        }
    }
}

// ---------------------------------------------------------------------------
// Fused MFMA chain LLg->LL3->LL4, single shared tile; stage-1 A staged
// through LDS with COALESCED global loads (fixes per-lane row reads).
// ---------------------------------------------------------------------------
#define MLL_EPI(O0,O1,ACC0,ACC1,BIAS,SPTR) { \
    const float es_ = expf((SPTR)[0]); \
    const float bv0_ = (BIAS)[c0], bv1_ = (BIAS)[c1]; \
    float p_[16]; \
    _Pragma("unroll") for (int r = 0; r < 16; ++r){ \
        O0[r] = ACC0[r] + bv0_; O1[r] = ACC1[r] + bv1_; \
        p_[r] = O0[r]*O0[r] + O1[r]*O1[r]; } \
    _Pragma("unroll") for (int m_ = 1; m_ < 32; m_ <<= 1){ \
        _Pragma("unroll") for (int r = 0; r < 16; ++r) p_[r] += __shfl_xor(p_[r], m_, 64); } \
    if (l31 == 0){ \
        _Pragma("unroll") for (int r = 0; r < 16; ++r){ \
            int row = (r&3) + 8*(r>>2) + 4*h; \
            float v = p_[r]; \
            if (w == 0){ v -= O0[r]*O0[r]; y0v[row] = O0[r]; } \
            psum[w][row] = v; } } \
    __syncthreads(); \
    _Pragma("unroll") for (int r = 0; r < 16; ++r){ \
        int row = (r&3) + 8*(r>>2) + 4*h; \
        float S_ = psum[0][row] + psum[1][row] + psum[2][row]; \
        float y0_ = y0v[row]; \
        float tv_ = es_ / (1.f + expf(-y0_)) + 1.1f; \
        float dn_ = fmaxf(S_, 1e-8f); \
        float sq_ = sqrtf((tv_*tv_ - 1.f)/dn_); \
        O0[r] *= sq_; O1[r] *= sq_; \
        if (w == 0 && l31 == 0) O0[r] = tv_; } \
    __syncthreads(); }

#define GSPLIT8(SRC,AH,AL) { \
    _Pragma("unroll") for (int e_ = 0; e_ < 8; ++e_){ \
        float gg_ = gelu_f((SRC)[e_]); \
        _Float16 hi_ = (_Float16)gg_; \
        AH[e_] = hi_; AL[e_] = (_Float16)(gg_ - (float)hi_); } }

__global__ __launch_bounds__(192) void mfuse_kernel(
    const float* __restrict__ Hrm, const float* __restrict__ Msg,
    const unsigned short* __restrict__ Wgh, const unsigned short* __restrict__ Wgl,
    const unsigned short* __restrict__ W3h, const unsigned short* __restrict__ W3l,
    const unsigned short* __restrict__ W4h, const unsigned short* __restrict__ W4l,
    const float* __restrict__ bg, const float* __restrict__ sg,
    const float* __restrict__ b3, const float* __restrict__ s3,
    const float* __restrict__ b4, const float* __restrict__ s4,
    const float* __restrict__ x, float* __restrict__ out)
{
    __shared__ float psum[3][32], y0v[32];
    __shared__ float tile[32*198];          // stage-2/3 fp32 tile; stage-1 reuses as fp16 stage bufs

    const int tid = threadIdx.x;
    const int w = tid >> 6, lane = tid & 63, l31 = lane & 31, h = lane >> 5;
    const int bid = blockIdx.x;
    const int b = bid / NMT, mt = bid % NMT;
    const int row0 = mt*32;
    const int nb = w*64;
    const int c0 = nb + l31, c1 = nb + 32 + l31;

    float o0[16], o1[16];
    float xa0[16], xa1[16];   // stage-1 outputs (X2f) kept for LL4 residual

    // ---------------- Stage 1: LLg (K=384, A staged in LDS, coalesced) ------
    {
        unsigned short* lAh = (unsigned short*)tile;         // [32][104] shorts
        unsigned short* lAl = lAh + 32*104;                  // [32][104] shorts
        f32x16 acc0 = ZERO16, acc1 = ZERO16;
        for (int ch = 0; ch < 4; ++ch){
            __syncthreads();
            const float* srcb = (ch < 2) ? Hrm : Msg;
            const int kk0 = (ch & 1) * 96;
            #pragma unroll
            for (int r = 0; r < 4; ++r){
                int e = tid + r*192;          // 768 float4 = 32 rows x 24 quads
                int rl = e / 24, q = e - rl*24;
                float4 v = *(const float4*)&srcb[((size_t)b*NPIX + row0 + rl)*192 + kk0 + q*4];
                float g0 = gelu_f(v.x), g1 = gelu_f(v.y), g2 = gelu_f(v.z), g3 = gelu_f(v.w);
                _Float16 h0 = (_Float16)g0, h1g = (_Float16)g1, h2g = (_Float16)g2, h3g = (_Float16)g3;
                uint2 hv, lv;
                hv.x = (unsigned)h2u(h0)  | ((unsigned)h2u(h1g) << 16);
                hv.y = (unsigned)h2u(h2g) | ((unsigned)h2u(h3g) << 16);
                lv.x = (unsigned)h2u((_Float16)(g0 - (float)h0))  | ((unsigned)h2u((_Float16)(g1 - (float)h1g)) << 16);
                lv.y = (unsigned)h2u((_Float16)(g2 - (float)h2g)) | ((unsigned)h2u((_Float16)(g3 - (float)h3g)) << 16);
                *(uint2*)&lAh[rl*104 + q*4] = hv;
                *(uint2*)&lAl[rl*104 + q*4] = lv;
            }
            __syncthreads();
            #pragma unroll
            for (int k6 = 0; k6 < 6; ++k6){
                const int kloc = k6*16 + h*8;
                const int kb = ch*96 + kloc;
                f16x8 ah = __builtin_bit_cast(f16x8, *(const uint4*)&lAh[l31*104 + kloc]);
                f16x8 al = __builtin_bit_cast(f16x8, *(const uint4*)&lAl[l31*104 + kloc]);
                f16x8 wh0 = __builtin_bit_cast(f16x8, *(const uint4*)&Wgh[(size_t)c0*384 + kb]);
                f16x8 wl0 = __builtin_bit_cast(f16x8, *(const uint4*)&Wgl[(size_t)c0*384 + kb]);
                f16x8 wh1 = __builtin_bit_cast(f16x8, *(const uint4*)&Wgh[(size_t)c1*384 + kb]);
                f16x8 wl1 = __builtin_bit_cast(f16x8, *(const uint4*)&Wgl[(size_t)c1*384 + kb]);
                MF(acc0, ah, wh0) MF(acc0, al, wh0) MF(acc0, ah, wl0)
                MF(acc1, ah, wh1) MF(acc1, al, wh1) MF(acc1, ah, wl1)
            }
        }
        MLL_EPI(o0, o1, acc0, acc1, bg, sg)
        #pragma unroll
        for (int r = 0; r < 16; ++r){
            int row = (r&3) + 8*(r>>2) + 4*h;
            tile[row*198 + c0] = o0[r];
            tile[row*198 + c1] = o1[r];
            xa0[r] = o0[r];
            xa1[r] = o1[r];
        }
        __syncthreads();
    }

    // ---------------- Stage 2: LL3 (K=192, A = gelu(tile)) ----------------
    {
        f32x16 acc0 = ZERO16, acc1 = ZERO16;
        #pragma unroll
        for (int ks = 0; ks < 12; ++ks){
            const int kb = ks*16 + h*8;
            float g[8];
            #pragma unroll
            for (int e = 0; e < 8; ++e) g[e] = tile[l31*198 + kb + e];
            f16x8 ah, al;
            GSPLIT8(g, ah, al)
            f16x8 wh0 = __builtin_bit_cast(f16x8, *(const uint4*)&W3h[(size_t)c0*192 + kb]);
            f16x8 wl0 = __builtin_bit_cast(f16x8, *(const uint4*)&W3l[(size_t)c0*192 + kb]);
            f16x8 wh1 = __builtin_bit_cast(f16x8, *(const uint4*)&W3h[(size_t)c1*192 + kb]);
            f16x8 wl1 = __builtin_bit_cast(f16x8, *(const uint4*)&W3l[(size_t)c1*192 + kb]);
            MF(acc0, ah, wh0) MF(acc0, al, wh0) MF(acc0, ah, wl0)
            MF(acc1, ah, wh1) MF(acc1, al, wh1) MF(acc1, ah, wl1)
        }
        MLL_EPI(o0, o1, acc0, acc1, b3, s3)
        #pragma unroll
        for (int r = 0; r < 16; ++r){
            int row = (r&3) + 8*(r>>2) + 4*h;
            tile[row*198 + c0] = o0[r];
            tile[row*198 + c1] = o1[r];
        }
        __syncthreads();
    }

    // ---------------- Stage 3: LL4 (K=192, A = gelu(tile)) ----------------
    {
        f32x16 acc0 = ZERO16, acc1 = ZERO16;
        #pragma unroll
        for (int ks = 0; ks < 12; ++ks){
            const int kb = ks*16 + h*8;
            float g[8];
            #pragma unroll
            for (int e = 0; e < 8; ++e) g[e] = tile[l31*198 + kb + e];
            f16x8 ah, al;
            GSPLIT8(g, ah, al)
            f16x8 wh0 = __builtin_bit_cast(f16x8, *(const uint4*)&W4h[(size_t)c0*192 + kb]);
            f16x8 wl0 = __builtin_bit_cast(f16x8, *(const uint4*)&W4l[(size_t)c0*192 + kb]);
            f16x8 wh1 = __builtin_bit_cast(f16x8, *(const uint4*)&W4h[(size_t)c1*192 + kb]);
            f16x8 wl1 = __builtin_bit_cast(f16x8, *(const uint4*)&W4l[(size_t)c1*192 + kb]);
            MF(acc0, ah, wh0) MF(acc0, al, wh0) MF(acc0, ah, wl0)
            MF(acc1, ah, wh1) MF(acc1, al, wh1) MF(acc1, ah, wl1)
        }
        MLL_EPI(o0, o1, acc0, acc1, b4, s4)
        // residuals: X2f (registers) + x (global col-major)
        #pragma unroll
        for (int r = 0; r < 16; ++r){ o0[r] += xa0[r]; o1[r] += xa1[r]; }
        #pragma unroll
        for (int p4 = 0; p4 < 4; ++p4){
            float4 xv0 = *(const float4*)&x[((size_t)b*192 + c0)*NPIX + row0 + 8*p4 + 4*h];
            float4 xv1 = *(const float4*)&x[((size_t)b*192 + c1)*NPIX + row0 + 8*p4 + 4*h];
            o0[4*p4+0] += xv0.x; o0[4*p4+1] += xv0.y; o0[4*p4+2] += xv0.z; o0[4*p4+3] += xv0.w;
            o1[4*p4+0] += xv1.x; o1[4*p4+1] += xv1.y; o1[4*p4+2] += xv1.z; o1[4*p4+3] += xv1.w;
        }
        #pragma unroll
        for (int p4 = 0; p4 < 4; ++p4){
            *(float4*)&out[((size_t)b*192 + c0)*NPIX + row0 + 8*p4 + 4*h] =
                make_float4(o0[4*p4+0], o0[4*p4+1], o0[4*p4+2], o0[4*p4+3]);
            *(float4*)&out[((size_t)b*192 + c1)*NPIX + row0 + 8*p4 + 4*h] =
                make_float4(o1[4*p4+0], o1[4*p4+1], o1[4*p4+2], o1[4*p4+3]);
        }
    }
}

// ---------------------------------------------------------------------------
// MFMA kNN screen (R21 double-buffered version).
// ---------------------------------------------------------------------------
__global__ __launch_bounds__(256) __attribute__((amdgpu_waves_per_eu(2))) void knn_kernel(
    const unsigned short* __restrict__ Xh, const unsigned short* __restrict__ S2h,
    unsigned* __restrict__ PK)
{
    __shared__ uint4 lds[2][640];

    const int tid  = threadIdx.x;
    const int lane = tid & 63;
    const int w    = tid >> 6;
    const int l31  = lane & 31;
    const int h    = lane >> 5;
    const int bid  = blockIdx.x;
    const int b    = bid & 7;
    const int t2   = bid >> 3;
    const int itile = t2 >> 3;
    const int sp    = t2 & 7;
    const int i0    = itile * 128;
    const int g0 = (sp*25)/NSP, g1 = ((sp+1)*25)/NSP;
    const size_t rowb = (size_t)b * NPAD;

    const size_t bbase = (rowb + i0 + w*32 + l31)*192;
    f16x8 B[6][2];
    #pragma unroll
    for (int kc = 0; kc < 6; ++kc)
        #pragma unroll
        for (int ks = 0; ks < 2; ++ks)
            B[kc][ks] = __builtin_bit_cast(f16x8, *(const uint4*)&Xh[bbase + kc*32 + (ks*2 + h)*8]);

    unsigned t_k0=0,t_k1=0,t_k2=0,t_k3=0,t_k4=0,t_k5=0,
             t_k6=0,t_k7=0,t_k8=0,t_k9=0,t_k10=0,t_k11=0;
    float thrf = -FINF;

    const int rs0 = tid >> 2, seg0 = tid & 3;
    const int wr0 = rs0*5 + seg0, wr1 = (rs0 + 64)*5 + seg0;

    uint4 pv0 = *(const uint4*)&Xh[(rowb + g0*128 + rs0)*192 + seg0*8];
    uint4 pv1 = *(const uint4*)&Xh[(rowb + g0*128 + rs0 + 64)*192 + seg0*8];

    for (int g = g0; g < g1; ++g){
        const int jg = g*128;
        f32x16 acc0 = ZERO16, acc1 = ZERO16, acc2 = ZERO16, acc3 = ZERO16;

        #pragma unroll
        for (int kc = 0; kc < 6; ++kc){
            const int buf = kc & 1;
            lds[buf][wr0] = pv0;
            lds[buf][wr1] = pv1;
            {
                int nkc = (kc < 5) ? kc + 1 : 0;
                int njg = (kc < 5) ? jg : jg + 128;
                if (kc < 5 || g + 1 < g1){
                    pv0 = *(const uint4*)&Xh[(rowb + njg + rs0)*192 + nkc*32 + seg0*8];
                    pv1 = *(const uint4*)&Xh[(rowb + njg + rs0 + 64)*192 + nkc*32 + seg0*8];
                }
            }
            __syncthreads();
            #pragma unroll
            for (int ks = 0; ks < 2; ++ks){
                int rb = l31*5 + (ks*2 + h);
                f16x8 bh = B[kc][ks];
                f16x8 a0h = __builtin_bit_cast(f16x8, lds[buf][  0 + rb]);
                f16x8 a1h = __builtin_bit_cast(f16x8, lds[buf][160 + rb]);
                f16x8 a2h = __builtin_bit_cast(f16x8, lds[buf][320 + rb]);
                f16x8 a3h = __builtin_bit_cast(f16x8, lds[buf][480 + rb]);
                MF(acc0, a0h, bh)
                MF(acc1, a1h, bh)
                MF(acc2, a2h, bh)
                MF(acc3, a3h, bh)
            }
        }

        {
            unsigned m  = (h == 0) ? 0xFFFFFFFFu : 0u;
            unsigned om = 0x3C00u & m;
            f16x8 one = __builtin_bit_cast(f16x8, make_uint4(om, 0, 0, 0));
            unsigned s0 = (unsigned)S2h[rowb + jg +  0 + l31];
            unsigned s1 = (unsigned)S2h[rowb + jg + 32 + l31];
            unsigned s2 = (unsigned)S2h[rowb + jg + 64 + l31];
            unsigned s3 = (unsigned)S2h[rowb + jg + 96 + l31];
            f16x8 a;
            a = __builtin_bit_cast(f16x8, make_uint4(s0 & m, 0,0,0)); MF(acc0, a, one)
            a = __builtin_bit_cast(f16x8, make_uint4(s1 & m, 0,0,0)); MF(acc1, a, one)
            a = __builtin_bit_cast(f16x8, make_uint4(s2 & m, 0,0,0)); MF(acc2, a, one)
            a = __builtin_bit_cast(f16x8, make_uint4(s3 & m, 0,0,0)); MF(acc3, a, one)
        }

        INSACCK(acc0, 0)
        INSACCK(acc1, 1)
        INSACCK(acc2, 2)
        INSACCK(acc3, 3)
        thrf = (t_k11 != 0u) ? unmono(t_k11 & 0xFFFFF000u) : -FINF;
    }

    #define MRGK(Kk) { unsigned ok_ = __shfl((int)(Kk), lane ^ 32, 64); \
                      if (lane < 32) { INSKEY((unsigned)ok_) } }
    MRGK(t_k0) MRGK(t_k1) MRGK(t_k2) MRGK(t_k3) MRGK(t_k4) MRGK(t_k5)
    MRGK(t_k6) MRGK(t_k7) MRGK(t_k8) MRGK(t_k9) MRGK(t_k10) MRGK(t_k11)

    if (lane < 32){
        size_t po = ((size_t)(t2*8 + b)*128 + (size_t)w*32 + l31)*12;
        PK[po+ 0] = t_k0;  PK[po+ 1] = t_k1;  PK[po+ 2] = t_k2;  PK[po+ 3] = t_k3;
        PK[po+ 4] = t_k4;  PK[po+ 5] = t_k5;  PK[po+ 6] = t_k6;  PK[po+ 7] = t_k7;
        PK[po+ 8] = t_k8;  PK[po+ 9] = t_k9;  PK[po+10] = t_k10; PK[po+11] = t_k11;
    }
}

// ---------------------------------------------------------------------------
// 8-way key merge -> approx top-16 -> exact fp32 rescore -> top-9
// -> max-message, Msg fp32 ROW-MAJOR [m][192].
// ---------------------------------------------------------------------------
__global__ __launch_bounds__(256) void merge_msg_kernel(
    const float* __restrict__ H, const float* __restrict__ SQf,
    const unsigned* __restrict__ PK, float* __restrict__ Msg)
{
    __shared__ float liX[16*196];
    __shared__ unsigned kv[1600];
    __shared__ float cd[256];
    __shared__ int   cidx[256];
    __shared__ int   fidx[144];

    const int tid = threadIdx.x;
    const int bid = blockIdx.x;
    const int b  = bid / 196;
    const int i0 = (bid % 196) * 16;
    const int base = b * NPIX;

    #pragma unroll
    for (int k = 0; k < 3; ++k){
        int f = tid + k*256;
        int r = f / 48, c4 = f % 48;
        *(float4*)&liX[r*196 + c4*4] = *(const float4*)&H[(size_t)(base + i0 + r)*192 + c4*4];
    }
    if (tid < 128){
        int r = tid >> 3, sp = tid & 7;
        int i = i0 + r;
        size_t po = ((size_t)(((i>>7)*NSP + sp)*8 + b)*128 + (i & 127))*12;
        #pragma unroll
        for (int q = 0; q < 3; ++q)
            *(uint4*)&kv[r*100 + sp*12 + q*4] = *(const uint4*)&PK[po + q*4];
    }
    __syncthreads();

    if (tid < 16){
        int r = tid;
        int h0=0,h1=0,h2=0,h3=0,h4=0,h5=0,h6=0,h7=0;
        #pragma unroll
        for (int p = 0; p < 16; ++p){
            unsigned bk = 0; int bs = 0;
#define HEADC(SP,HV) { \
            unsigned k_ = (HV < 12) ? kv[r*100 + SP*12 + HV] : 0u; \
            bool bt_ = k_ > bk; \
            bk = bt_? k_ : bk; bs = bt_? SP : bs; }
            HEADC(0,h0) HEADC(1,h1) HEADC(2,h2) HEADC(3,h3)
            HEADC(4,h4) HEADC(5,h5) HEADC(6,h6) HEADC(7,h7)
#undef HEADC
            cidx[r*16 + p] = 4095 - (int)(bk & 0xFFFu);
            h0 += (bs==0); h1 += (bs==1); h2 += (bs==2); h3 += (bs==3);
            h4 += (bs==4); h5 += (bs==5); h6 += (bs==6); h7 += (bs==7);
        }
    }
    __syncthreads();

    {
        int r = tid >> 4, p = tid & 15;
        int j = cidx[r*16 + p];
        const float* hj = &H[(size_t)(base + j)*192];
        float dot = 0.f;
        #pragma unroll
        for (int q = 0; q < 48; ++q){
            float4 xv = *(const float4*)&liX[r*196 + q*4];
            float4 yv = *(const float4*)&hj[q*4];
            dot = fmaf(xv.x,yv.x, fmaf(xv.y,yv.y, fmaf(xv.z,yv.z, fmaf(xv.w,yv.w, dot))));
        }
        cd[r*16 + p] = SQf[base + j] - 2.f*dot;
    }
    __syncthreads();

    if (tid < 16){
        int r = tid;
        Top9 m; m.init();
        #pragma unroll
        for (int c = 0; c < 16; ++c) m.insert(cd[r*16 + c], cidx[r*16 + c]);
        fidx[r*9+0]=m.j0; fidx[r*9+1]=m.j1; fidx[r*9+2]=m.j2; fidx[r*9+3]=m.j3;
        fidx[r*9+4]=m.j4; fidx[r*9+5]=m.j5; fidx[r*9+6]=m.j6; fidx[r*9+7]=m.j7;
        fidx[r*9+8]=m.j8;
    }
    __syncthreads();

    int rr = tid >> 4, part = tid & 15;
    int ii = i0 + rr;
    int nbr[9];
    #pragma unroll
    for (int e = 0; e < 9; ++e) nbr[e] = fidx[rr*9 + e];
    #pragma unroll
    for (int q = 0; q < 3; ++q){
        float4 mv = make_float4(-FINF, -FINF, -FINF, -FINF);
        #pragma unroll
        for (int e = 0; e < 9; ++e){
            float4 v = *(const float4*)&H[(size_t)(base + nbr[e])*192 + part*12 + q*4];
            mv.x = fmaxf(mv.x, v.x); mv.y = fmaxf(mv.y, v.y);
            mv.z = fmaxf(mv.z, v.z); mv.w = fmaxf(mv.w, v.w);
        }
        float4 xi = *(const float4*)&liX[rr*196 + part*12 + q*4];
        *(float4*)&Msg[(size_t)(base + ii)*192 + part*12 + q*4] =
            make_float4(mv.x - xi.x, mv.y - xi.y, mv.z - xi.z, mv.w - xi.w);
    }
}

extern "C" void kernel_launch(void* const* d_in, const int* in_sizes, int n_in,
                              void* d_out, int out_size, void* d_ws, size_t ws_size,
                              hipStream_t stream)
{
    const float* x  = (const float*)d_in[0];
    const float* W1 = (const float*)d_in[1];
    const float* b1 = (const float*)d_in[2];
    const float* s1 = (const float*)d_in[3];
    const float* W2 = (const float*)d_in[4];
    const float* b2 = (const float*)d_in[5];
    const float* s2 = (const float*)d_in[6];
    const float* Wg = (const float*)d_in[7];
    const float* bg = (const float*)d_in[8];
    const float* sg = (const float*)d_in[9];
    const float* W3 = (const float*)d_in[10];
    const float* b3 = (const float*)d_in[11];
    const float* s3 = (const float*)d_in[12];
    const float* W4 = (const float*)d_in[13];
    const float* b4 = (const float*)d_in[14];
    const float* s4 = (const float*)d_in[15];
    float* ws = (float*)d_ws;
    float* out = (float*)d_out;

    const size_t NE = (size_t)NB*NPIX*192;
    float* T1cm = ws;
    float* Msg  = ws;
    float* Hrm  = ws + NE;
    unsigned short* Xh  = (unsigned short*)(ws + 3*NE);
    unsigned short* S2h = Xh + (size_t)NB*NPAD*192;
    float* SQf = (float*)(S2h + (size_t)NB*NPAD);
    unsigned* PK = (unsigned*)(SQf + (size_t)NB*NPIX);
    float* W1T = (float*)(PK + (size_t)GRID_KNN*128*12);
    float* W2T = W1T + 36864;
    unsigned short* Wh16 = (unsigned short*)(W2T + 36864);
    unsigned short* Wl16 = Wh16 + 147456;
    const unsigned short* Wgh = Wh16,          *Wgl = Wl16;
    const unsigned short* W3h = Wh16 + 73728,  *W3l = Wl16 + 73728;
    const unsigned short* W4h = Wh16 + 110592, *W4l = Wl16 + 110592;

    wt_kernel<<<72, 256, 0, stream>>>(W1, W2, W1T, W2T);
    wt16_kernel<<<576, 256, 0, stream>>>(Wg, W3, W4, Wh16, Wl16);
    pad_kernel<<<NB, 256, 0, stream>>>(Xh, S2h);
    // LL1 (FMA): x -> T1cm
    ll2_kernel<192, true , false, false, false><<<GRID_LL, 256, 0, stream>>>(
        x, x, W1T, b1, s1, nullptr, T1cm, nullptr, nullptr, nullptr, nullptr);
    // LL2 (FMA): T1cm -> Hrm (+x residual) + conv outputs
    ll2_kernel<192, false, true , true , true ><<<GRID_LL, 256, 0, stream>>>(
        T1cm, T1cm, W2T, b2, s2, x, nullptr, Hrm, Xh, S2h, SQf);
    // graph conv
    knn_kernel<<<GRID_KNN, 256, 0, stream>>>(Xh, S2h, PK);
    merge_msg_kernel<<<GRID_MSG, 256, 0, stream>>>(Hrm, SQf, PK, Msg);
    // fused LLg -> LL3 -> LL4 (MFMA), output col-major = (B,C,H,W) native
    mfuse_kernel<<<GRID_LL, 192, 0, stream>>>(
        Hrm, Msg, Wgh, Wgl, W3h, W3l, W4h, W4l,
        bg, sg, b3, s3, b4, s4, x, out);
}